// Round 15
// baseline (117.631 us; speedup 1.0000x reference)
//
#include <hip/hip_runtime.h>
#include <math.h>

#define SMOOTH 1e-4f
#define BN_EPS 1e-5f

constexpr int Bn = 8;
constexpr int Cc = 256;
constexpr int Nn = 1024;   // H*W
constexpr int G = 8;       // heads
constexpr int INNER = 512;
constexpr int OC = 1536;   // 3*INNER
constexpr int KK = 2304;   // 9*256 im2col K

typedef unsigned short u16;
typedef __bf16 bf16x8 __attribute__((ext_vector_type(8)));
typedef float f32x4 __attribute__((ext_vector_type(4)));
typedef unsigned short us8 __attribute__((ext_vector_type(8)));
typedef unsigned short us4 __attribute__((ext_vector_type(4)));

__device__ __forceinline__ u16 f2bf(float f) {
  unsigned int u = __float_as_uint(f);
  unsigned int r = (u + 0x7fffu + ((u >> 16) & 1u)) >> 16;
  return (u16)r;
}
__device__ __forceinline__ float bf2f(u16 u) {
  return __uint_as_float(((unsigned int)u) << 16);
}

__device__ __forceinline__ float waveSum(float v) {
#pragma unroll
  for (int off = 32; off > 0; off >>= 1) v += __shfl_xor(v, off, 64);
  return v;
}

__device__ __forceinline__ void gl16(const u16* g, u16* l) {
  __builtin_amdgcn_global_load_lds(
      (const __attribute__((address_space(1))) unsigned int*)g,
      (__attribute__((address_space(3))) unsigned int*)l, 16, 0, 0);
}

__device__ __forceinline__ bf16x8 ld8(const u16* p) {
  return __builtin_bit_cast(bf16x8, *reinterpret_cast<const us8*>(p));
}

// raw barrier with compiler fences (no vmcnt/lgkm drain)
__device__ __forceinline__ void barrier_raw() {
  asm volatile("" ::: "memory");
  __builtin_amdgcn_s_barrier();
  asm volatile("" ::: "memory");
  __builtin_amdgcn_sched_barrier(0);
}

// swizzled LDS fragment read: rows of 64 u16, u16idx ^ ((row&7)<<3)
__device__ __forceinline__ bf16x8 ldfrag(const u16* base, int row, int col) {
  int idx = (row * 64 + col) ^ ((row & 7) << 3);
  return ld8(base + idx);
}

// ---------------------------------------------------------------------------
// merged prep: [0,1536) wconv | [1536,1600) wout repack (+zpage init) |
// [1600,2112) x->xT bf16 transpose | [2112,2120) pbtab. (unchanged)
// ---------------------------------------------------------------------------
__global__ __launch_bounds__(256) void prep_kernel(
    const float* __restrict__ wq, const float* __restrict__ wout,
    const float* __restrict__ x, const float* __restrict__ head_scale,
    u16* __restrict__ wA, u16* __restrict__ wB, u16* __restrict__ xT,
    u16* __restrict__ zpage, float* __restrict__ etab,
    float* __restrict__ idn) {
  __shared__ __align__(16) char smraw[9216];
  const int bid = blockIdx.x;
  const int tid = threadIdx.x;

  if (bid < 1536) {  // ---- wconv: wA[oc][tap*256+ic] ----
    float* sw = (float*)smraw;
    const int oc = bid;
    for (int i = tid; i < KK; i += 256) sw[i] = wq[(size_t)oc * KK + i];
    __syncthreads();
#pragma unroll
    for (int j = 0; j < 2; ++j) {
      int c8 = tid + j * 256;
      if (c8 < KK / 8) {
        us8 v;
#pragma unroll
        for (int e = 0; e < 8; ++e) {
          int k = c8 * 8 + e;
          int tap = k >> 8, ic = k & 255;
          v[e] = f2bf(sw[ic * 9 + tap]);
        }
        *reinterpret_cast<us8*>(wA + (size_t)oc * KK + c8 * 8) = v;
      }
    }
  } else if (bid < 1600) {  // ---- wout repack (+ zero page, 512 B) ----
    const int idx = (bid - 1536) * 256 + tid;
    const float4 a = reinterpret_cast<const float4*>(wout)[idx * 2];
    const float4 b = reinterpret_cast<const float4*>(wout)[idx * 2 + 1];
    us8 v;
    v[0] = f2bf(a.x); v[1] = f2bf(a.y); v[2] = f2bf(a.z); v[3] = f2bf(a.w);
    v[4] = f2bf(b.x); v[5] = f2bf(b.y); v[6] = f2bf(b.z); v[7] = f2bf(b.w);
    reinterpret_cast<us8*>(wB)[idx] = v;
    if (bid == 1536) zpage[tid] = 0;
  } else if (bid < 2112) {  // ---- x [b][ic][n] f32 -> xT [b][pix][ic] bf16 ----
    u16* sxt = (u16*)smraw;  // [32 px][136] u16
    const int lb = bid - 1600;
    const int b = lb >> 6;
    const int nt = (lb >> 1) & 31;
    const int icc = lb & 1;
    const int n0 = nt * 32;
    const int ic0 = icc * 128;
    const float* xb = x + (size_t)b * Cc * Nn;
    {
      const int px = tid & 31;
      const int ic8 = tid >> 5;
#pragma unroll
      for (int i2 = 0; i2 < 16; ++i2) {
        const int ic = ic8 * 16 + i2;
        sxt[px * 136 + ic] = f2bf(xb[(size_t)(ic0 + ic) * Nn + n0 + px]);
      }
    }
    __syncthreads();
    const int c8 = tid & 7;
    const int px = tid >> 3;
    u16* dst = xT + (((size_t)b * 1024 + n0 + px) * 256) + ic0 + c8 * 8;
#pragma unroll
    for (int c32 = 0; c32 < 2; ++c32)
      *reinterpret_cast<us8*>(dst + c32 * 64) =
          *reinterpret_cast<const us8*>(sxt + px * 136 + c32 * 64 + c8 * 8);
  } else {  // ---- pbtab ----
    float* et = (float*)smraw;
    float* rsum = (float*)smraw + 64;
    const int g = bid - 2112;
    const float hs = head_scale[g];
    const float sg = 1.f / (1.f + __expf(-hs));
    const float s = sg * (0.4f - 0.003f) + 0.003f;
    const float sf = 1.f / (2.f * s * s);
    if (tid < 64) {
      float v = 0.f;
      if (tid < 63) {
        float d = (float)(tid - 31) * (1.f / 32.f);
        v = __expf(-sf * d * d);
      }
      et[tid] = v;
      etab[g * 64 + tid] = v;
    }
    __syncthreads();
    if (tid < 32) {
      float sum = 0.f;
#pragma unroll
      for (int ym = 0; ym < 32; ++ym) sum += et[tid - ym + 31];
      rsum[tid] = sum;
    }
    __syncthreads();
    for (int i = tid; i < 1024; i += 256)
      idn[g * 1024 + i] = 1.f / (rsum[i >> 5] * rsum[i & 31]);
  }
}

// ---------------------------------------------------------------------------
// qkv implicit GEMM (unchanged from R14). grid = 256, XCD-swizzled.
// ---------------------------------------------------------------------------
__global__ __launch_bounds__(512, 1) void qkv_gemm_kernel(
    const u16* __restrict__ wA, const u16* __restrict__ xT,
    const u16* __restrict__ zpage, const float* __restrict__ idn,
    u16* __restrict__ qt, u16* __restrict__ ktp, u16* __restrict__ vt) {
  const int tid = threadIdx.x;
  const int lane = tid & 63;
  const int wv = tid >> 6;
  const int wm = wv >> 2, wn = wv & 3;
  const int h = lane >> 4, l15 = lane & 15;
  const int wgid = ((int)blockIdx.x & 7) * 32 + ((int)blockIdx.x >> 3);
  const int bm = wgid & 7;
  const int bn = wgid >> 3;
  const int m0 = bm * 192;

  __shared__ __align__(16) u16 smem[57344];

  const int arow = tid >> 3;
  const int aslot = (tid & 7) ^ (arow & 7);
  const u16* gA0 = wA + (size_t)(m0 + arow) * KK + aslot * 8;
  const int bslot8 = ((tid & 3) ^ (((tid >> 2) & 3) ^ ((tid >> 4) & 3))) * 8;
  const int pimgBase = ((bn & 3) << 8) + (tid >> 2);
  const u16* xTb = xT + (size_t)(bn >> 2) * (1024 * 256);

  auto mkSrc = [&](int tap, int pass) -> const u16* {
    const int dyq = (tap * 11) >> 5;
    const int ddx = tap - 3 * dyq - 1;
    const int ddy = dyq - 1;
    const int pimg = pimgBase + pass * 128;
    const int sx = (pimg & 31) + ddx;
    const int sy = (pimg >> 5) + ddy;
    if (((unsigned)sx < 32u) && ((unsigned)sy < 32u))
      return xTb + (size_t)(pimg + ddx + ddy * 32) * 256 + bslot8;
    return zpage;
  };
  const u16* srcB0 = mkSrc(0, 0);
  const u16* srcB1 = mkSrc(0, 1);
  int koff = 0;

  const int aX = l15 & 7;
  const int bX = (l15 & 3) ^ ((l15 >> 2) & 3);
  const u16* aBase = smem + (wm * 96 + l15) * 64;
  const u16* bBase = smem + 12288 + (wn * 64 + l15) * 32;
  const int slA0 = (h ^ aX) * 8;
  const int slA1 = ((4 + h) ^ aX) * 8;
  const int slB = (h ^ bX) * 8;

  f32x4 acc[6][4];
#pragma unroll
  for (int i = 0; i < 6; ++i)
#pragma unroll
    for (int j = 0; j < 4; ++j) acc[i][j] = (f32x4){0.f, 0.f, 0.f, 0.f};

  auto STAGE_A = [&](int pass, int dbuf, int kti) {
    gl16(gA0 + (size_t)pass * 64 * KK + kti * 64,
         smem + dbuf + pass * 4096 + tid * 8);
  };
  auto STAGE_B = [&](int kap, int pass, int dbuf) {
    gl16((pass ? srcB1 : srcB0) + koff + kap * 32,
         smem + dbuf + 12288 + kap * 8192 + pass * 4096 + tid * 8);
  };

  STAGE_A(0, 0, 0); STAGE_A(1, 0, 0); STAGE_A(2, 0, 0);
  STAGE_B(0, 0, 0); STAGE_B(0, 1, 0);
  STAGE_B(1, 0, 0); STAGE_B(1, 1, 0);
  asm volatile("s_waitcnt vmcnt(2)" ::: "memory");
  barrier_raw();

  bf16x8 af[3], bf[4];
#pragma unroll 1
  for (int kt = 0; kt < 36; ++kt) {
    const int buf = (kt & 1) * 28672;
    const int nbuf = 28672 - buf;
    const bool more = (kt < 35);

    if (more && (kt & 3) == 3) {
      const int ntap = (kt + 1) >> 2;
      srcB0 = mkSrc(ntap, 0);
      srcB1 = mkSrc(ntap, 1);
    }
    koff = ((kt + 1) & 3) << 6;

    // ---- P1 ----
#pragma unroll
    for (int ni = 0; ni < 4; ++ni) bf[ni] = ld8(bBase + buf + ni * 512 + slB);
#pragma unroll
    for (int q = 0; q < 3; ++q) af[q] = ld8(aBase + buf + q * 1024 + slA0);
    if (more) { STAGE_A(0, nbuf, kt + 1); STAGE_A(1, nbuf, kt + 1); }
    barrier_raw();
    __builtin_amdgcn_s_setprio(1);
#pragma unroll
    for (int q = 0; q < 3; ++q)
#pragma unroll
      for (int ni = 0; ni < 4; ++ni)
        acc[q][ni] = __builtin_amdgcn_mfma_f32_16x16x32_bf16(af[q], bf[ni], acc[q][ni], 0, 0, 0);
    __builtin_amdgcn_s_setprio(0);

    // ---- P2 ----
#pragma unroll
    for (int q = 0; q < 3; ++q) af[q] = ld8(aBase + buf + (3 + q) * 1024 + slA0);
    if (more) {
      STAGE_A(2, nbuf, kt + 1); STAGE_B(0, 0, nbuf);
      asm volatile("s_waitcnt vmcnt(4)" ::: "memory");
    } else {
      asm volatile("s_waitcnt vmcnt(0)" ::: "memory");
    }
    barrier_raw();
    __builtin_amdgcn_s_setprio(1);
#pragma unroll
    for (int q = 0; q < 3; ++q)
#pragma unroll
      for (int ni = 0; ni < 4; ++ni)
        acc[3 + q][ni] = __builtin_amdgcn_mfma_f32_16x16x32_bf16(af[q], bf[ni], acc[3 + q][ni], 0, 0, 0);
    __builtin_amdgcn_s_setprio(0);

    // ---- P3 ----
#pragma unroll
    for (int ni = 0; ni < 4; ++ni) bf[ni] = ld8(bBase + buf + 8192 + ni * 512 + slB);
#pragma unroll
    for (int q = 0; q < 3; ++q) af[q] = ld8(aBase + buf + q * 1024 + slA1);
    if (more) { STAGE_B(0, 1, nbuf); STAGE_B(1, 0, nbuf); }
    barrier_raw();
    __builtin_amdgcn_s_setprio(1);
#pragma unroll
    for (int q = 0; q < 3; ++q)
#pragma unroll
      for (int ni = 0; ni < 4; ++ni)
        acc[q][ni] = __builtin_amdgcn_mfma_f32_16x16x32_bf16(af[q], bf[ni], acc[q][ni], 0, 0, 0);
    __builtin_amdgcn_s_setprio(0);

    // ---- P4 ----
#pragma unroll
    for (int q = 0; q < 3; ++q) af[q] = ld8(aBase + buf + (3 + q) * 1024 + slA1);
    if (more) {
      STAGE_B(1, 1, nbuf);
      asm volatile("s_waitcnt vmcnt(2)" ::: "memory");
    }
    barrier_raw();
    __builtin_amdgcn_s_setprio(1);
#pragma unroll
    for (int q = 0; q < 3; ++q)
#pragma unroll
      for (int ni = 0; ni < 4; ++ni)
        acc[3 + q][ni] = __builtin_amdgcn_mfma_f32_16x16x32_bf16(af[q], bf[ni], acc[3 + q][ni], 0, 0, 0);
    __builtin_amdgcn_s_setprio(0);
  }

  const int b = bn >> 2;
  const int nimgBase = (bn & 3) * 256 + wn * 64;
  float ssF[4], ssH[4];
#pragma unroll
  for (int ni = 0; ni < 4; ++ni) {
    float sF = 0.f, sH = 0.f;
#pragma unroll
    for (int m4 = 0; m4 < 6; ++m4) {
      float s = 0.f;
#pragma unroll
      for (int r = 0; r < 4; ++r) s += acc[m4][ni][r] * acc[m4][ni][r];
      const bool isFull = (wm == 0) ? (m4 < 4) : (m4 >= 2);
      if (isFull) sF += s; else sH += s;
    }
    sF += __shfl_xor(sF, 16, 64); sF += __shfl_xor(sF, 32, 64);
    sH += __shfl_xor(sH, 16, 64); sH += __shfl_xor(sH, 32, 64);
    ssF[ni] = sF; ssH[ni] = sH;
  }
  float* xch = (float*)smem;
  if (h == 0) {
#pragma unroll
    for (int ni = 0; ni < 4; ++ni)
      xch[((wm * 4 + wn) * 4 + ni) * 16 + l15] = ssH[ni];
  }
  __syncthreads();
#pragma unroll
  for (int ni = 0; ni < 4; ++ni)
    ssH[ni] += xch[(((1 - wm) * 4 + wn) * 4 + ni) * 16 + l15];

  const int headF = (wm == 0) ? 3 * bm : 3 * bm + 2;
  const int headH = 3 * bm + 1;
  const int secF = headF >> 3, gF = headF & 7;
  const int secH = headH >> 3, gH = headH & 7;
  float rsF[4], rsH[4];
#pragma unroll
  for (int ni = 0; ni < 4; ++ni) {
    const int nimg = nimgBase + ni * 16 + l15;
    float rf = rsqrtf(ssF[ni] + SMOOTH);
    if (secF == 0) rf *= idn[gF * 1024 + nimg];
    rsF[ni] = rf;
    float rh = rsqrtf(ssH[ni] + SMOOTH);
    if (secH == 0) rh *= idn[gH * 1024 + nimg];
    rsH[ni] = rh;
  }
#pragma unroll
  for (int m4 = 0; m4 < 6; ++m4) {
    const bool isFull = (wm == 0) ? (m4 < 4) : (m4 >= 2);
    const int head = isFull ? headF : headH;
    const int sec = head >> 3, g = head & 7;
    const int d0 = isFull ? ((wm == 0) ? m4 * 16 : (m4 - 2) * 16)
                          : ((wm == 0) ? (m4 - 4) * 16 : 32 + m4 * 16);
    const size_t bg = (size_t)b * G + g;
    if (sec < 2) {
      u16* basep = (sec ? ktp : qt) + bg * 65536;
#pragma unroll
      for (int ni = 0; ni < 4; ++ni) {
        const float rs = isFull ? rsF[ni] : rsH[ni];
        const int nimg = nimgBase + ni * 16 + l15;
        us4 v;
        v[0] = f2bf(acc[m4][ni][0] * rs);
        v[1] = f2bf(acc[m4][ni][1] * rs);
        v[2] = f2bf(acc[m4][ni][2] * rs);
        v[3] = f2bf(acc[m4][ni][3] * rs);
        *reinterpret_cast<us4*>(basep + (size_t)nimg * 64 + d0 + 4 * h) = v;
      }
    } else {
      u16* basep = vt + bg * 65536;
#pragma unroll
      for (int ni = 0; ni < 4; ++ni) {
        const int nimg = nimgBase + ni * 16 + l15;
#pragma unroll
        for (int r = 0; r < 4; ++r)
          basep[(size_t)(d0 + 4 * h + r) * 1024 + nimg] = f2bf(acc[m4][ni][r]);
      }
    }
  }
}

// ---------------------------------------------------------------------------
// MFMA attention v2: QBLK=64, grid 1024 (4 blocks/CU), Q in REGISTERS,
// LDS = 40KB exactly (K dbuf 16K | V dbuf 16K | per-wave sP 8K). pb computed
// inline as ONE __expf per element (closer to reference than table product).
// XCD-swizzled: each XCD owns one head g.
// ---------------------------------------------------------------------------
__global__ __launch_bounds__(256, 4) void attn_mfma_kernel(
    const u16* __restrict__ qt, const u16* __restrict__ ktp,
    const u16* __restrict__ vt, const float* __restrict__ head_scale,
    u16* __restrict__ aout) {
  const int tid = threadIdx.x;
  const int lane = tid & 63;
  const int wv = tid >> 6;
  const int h = lane >> 4;
  const int l15 = lane & 15;
  const int wgid = (blockIdx.x & 7) * 128 + (blockIdx.x >> 3);
  const int g = wgid >> 7;        // one g per XCD
  const int b = (wgid >> 4) & 7;
  const int nb = wgid & 15;       // 16 chunks of 64 q-rows

  __shared__ __align__(16) u16 smem[20480];  // 40 KB exactly
  // K buf d: smem + d*4096 ; V buf d: smem + 8192 + d*4096
  u16* sP = smem + 16384 + wv * 1024;  // 16x64 per wave

  const size_t bg = (size_t)b * G + g;
  const u16* qg = qt + bg * 65536;
  const u16* kg = ktp + bg * 65536;
  const u16* vg = vt + bg * 65536;

  const float hs = head_scale[g];
  const float sg = 1.f / (1.f + __expf(-hs));
  const float sv = sg * (0.4f - 0.003f) + 0.003f;
  const float sf = 1.f / (2.f * sv * sv);

  const int srow = tid >> 3;
  const int scol = ((tid & 7) ^ (srow & 7)) * 8;

  // prologue: stage K/V tile 0 into buf0
#pragma unroll
  for (int pass = 0; pass < 2; ++pass) {
    gl16(kg + (size_t)(pass * 32 + srow) * 64 + scol,
         smem + pass * 2048 + tid * 8);
    gl16(vg + (size_t)(pass * 32 + srow) * 1024 + scol,
         smem + 8192 + pass * 2048 + tid * 8);
  }

  // Q fragments direct to registers (A-operand: rows n, k = d)
  const int col8 = h * 8;
  const int nbase = nb * 64 + wv * 16;
  bf16x8 aq[2];
#pragma unroll
  for (int kk = 0; kk < 2; ++kk)
    aq[kk] = ld8(qg + (size_t)(nbase + l15) * 64 + kk * 32 + col8);

  // per-lane query coords (r = 0..3 rows: n = nbase + 4h + r)
  float ynr[4], xnr[4];
#pragma unroll
  for (int r = 0; r < 4; ++r) {
    int n = nbase + 4 * h + r;
    ynr[r] = (float)(n >> 5);
    xnr[r] = (float)(n & 31);
  }
  const float xm0 = (float)l15, xm1 = (float)(l15 + 16);

  f32x4 oacc[4];
#pragma unroll
  for (int dj = 0; dj < 4; ++dj) oacc[dj] = (f32x4){0.f, 0.f, 0.f, 0.f};

  __syncthreads();  // K/V tile 0 landed

  for (int mt = 0; mt < 16; ++mt) {
    const u16* sKb = smem + (mt & 1) * 4096;
    const u16* sVb = smem + 8192 + (mt & 1) * 4096;
    if (mt < 15) {  // prefetch next tile into the other buffer
      const int nt2 = mt + 1;
      const int d = nt2 & 1;
#pragma unroll
      for (int pass = 0; pass < 2; ++pass) {
        gl16(kg + (size_t)(nt2 * 64 + pass * 32 + srow) * 64 + scol,
             smem + d * 4096 + pass * 2048 + tid * 8);
        gl16(vg + (size_t)(pass * 32 + srow) * 1024 + nt2 * 64 + scol,
             smem + 8192 + d * 4096 + pass * 2048 + tid * 8);
      }
    }

    // S = Q.K^T (16n x 64m per wave)
    f32x4 sacc[4];
#pragma unroll
    for (int tj = 0; tj < 4; ++tj) sacc[tj] = (f32x4){0.f, 0.f, 0.f, 0.f};
#pragma unroll
    for (int kk = 0; kk < 2; ++kk)
#pragma unroll
      for (int tj = 0; tj < 4; ++tj) {
        bf16x8 bk = ldfrag(sKb, tj * 16 + l15, kk * 32 + col8);
        sacc[tj] = __builtin_amdgcn_mfma_f32_16x16x32_bf16(aq[kk], bk, sacc[tj], 0, 0, 0);
      }

    // P = cos*idn * exp(-sf*dis) -> bf16 -> per-wave LDS
#pragma unroll
    for (int tj = 0; tj < 4; ++tj) {
      const float ymf = (float)(2 * mt + (tj >> 1));
      const float xmf = (tj & 1) ? xm1 : xm0;
#pragma unroll
      for (int r = 0; r < 4; ++r) {
        float dy = (ynr[r] - ymf) * (1.f / 32.f);
        float dx = (xnr[r] - xmf) * (1.f / 32.f);
        float wgt = sacc[tj][r] * __expf(-sf * (dy * dy + dx * dx));
        int nl = 4 * h + r;
        int pidx = (nl * 64 + tj * 16 + l15) ^ ((nl & 7) << 3);
        sP[pidx] = f2bf(wgt);
      }
    }

    // O += P.V
#pragma unroll
    for (int km = 0; km < 2; ++km) {
      bf16x8 ap = ldfrag(sP, l15, km * 32 + col8);
#pragma unroll
      for (int dj = 0; dj < 4; ++dj) {
        bf16x8 bvv = ldfrag(sVb, dj * 16 + l15, km * 32 + col8);
        oacc[dj] = __builtin_amdgcn_mfma_f32_16x16x32_bf16(ap, bvv, oacc[dj], 0, 0, 0);
      }
    }
    __syncthreads();  // next-tile loads landed + all waves done with this buf
  }

  // output: O (64n x 64d) via swizzled LDS (overlay K region, now dead)
  u16* sO = smem;  // 4096 u16 = 8KB
#pragma unroll
  for (int dj = 0; dj < 4; ++dj)
#pragma unroll
    for (int r = 0; r < 4; ++r) {
      int nl = wv * 16 + 4 * h + r;
      int idx = (nl * 64 + dj * 16 + l15) ^ ((nl & 7) << 3);
      sO[idx] = f2bf(oacc[dj][r]);
    }
  __syncthreads();
  {
    const int row = tid >> 2, c = (tid & 3) * 2;
    us8* dst = reinterpret_cast<us8*>(aout + (bg * 1024 + (size_t)nb * 64 + row) * 64);
#pragma unroll
    for (int k = 0; k < 2; ++k) {
      int idx = (row * 64 + (c + k) * 8) ^ ((row & 7) << 3);
      dst[c + k] = *reinterpret_cast<const us8*>(sO + idx);
    }
  }
}

// ---------------------------------------------------------------------------
// 1x1 conv as MFMA GEMM + fused deterministic BN partial stats. grid = 512.
// ---------------------------------------------------------------------------
__global__ __launch_bounds__(256, 4) void conv1x1_mfma_kernel(
    const u16* __restrict__ aout, const u16* __restrict__ wB,
    u16* __restrict__ proj, float* __restrict__ partials) {
  const int tid = threadIdx.x;
  const int lane = tid & 63;
  const int wv = tid >> 6;
  const int wr = wv >> 1, wc = wv & 1;
  const int h = lane >> 4, l15 = lane & 15;
  const int bm = blockIdx.x & 3;
  const int ntile = blockIdx.x >> 2;
  const int b = ntile >> 4;
  const int n0 = (ntile & 15) * 64;
  const int c0 = bm * 64;

  __shared__ __align__(16) u16 smem[16384];

  f32x4 acc[2][2];
#pragma unroll
  for (int i = 0; i < 2; ++i)
#pragma unroll
    for (int j = 0; j < 2; ++j) acc[i][j] = (f32x4){0.f, 0.f, 0.f, 0.f};

  const int srow = tid >> 3;
  const int scol = (tid & 7) * 8;

  auto STG = [&](int ks) {
    const int d = ks & 1;
#pragma unroll
    for (int pass = 0; pass < 2; ++pass) {
      gl16(wB + (size_t)(c0 + pass * 32 + srow) * 512 + ks * 64 + scol,
           smem + d * 4096 + pass * 2048 + tid * 8);
      gl16(aout + ((size_t)(b * G + ks) * 1024 + n0 + pass * 32 + srow) * 64 + scol,
           smem + 8192 + d * 4096 + pass * 2048 + tid * 8);
    }
  };

  STG(0);
  __syncthreads();
  for (int ks = 0; ks < 8; ++ks) {
    if (ks < 7) STG(ks + 1);
    const u16* sA = smem + (ks & 1) * 4096;
    const u16* sB = smem + 8192 + (ks & 1) * 4096;
#pragma unroll
    for (int kk = 0; kk < 2; ++kk) {
      bf16x8 af[2], bv[2];
#pragma unroll
      for (int mt = 0; mt < 2; ++mt)
        af[mt] = ld8(sA + (wr * 32 + mt * 16 + l15) * 64 + kk * 32 + h * 8);
#pragma unroll
      for (int nt = 0; nt < 2; ++nt)
        bv[nt] = ld8(sB + (wc * 32 + nt * 16 + l15) * 64 + kk * 32 + h * 8);
#pragma unroll
      for (int mt = 0; mt < 2; ++mt)
#pragma unroll
        for (int nt = 0; nt < 2; ++nt)
          acc[mt][nt] = __builtin_amdgcn_mfma_f32_16x16x32_bf16(af[mt], bv[nt], acc[mt][nt], 0, 0, 0);
    }
    __syncthreads();
  }

#pragma unroll
  for (int mt = 0; mt < 2; ++mt)
#pragma unroll
    for (int nt = 0; nt < 2; ++nt)
#pragma unroll
      for (int r = 0; r < 4; ++r) {
        const int c = c0 + wr * 32 + mt * 16 + 4 * h + r;
        const int n = n0 + wc * 32 + nt * 16 + l15;
        proj[((size_t)b * Cc + c) * Nn + n] = f2bf(acc[mt][nt][r]);
      }

  const int slab = ((b * 16 + (ntile & 15)) << 1) + wc;
#pragma unroll
  for (int mt = 0; mt < 2; ++mt)
#pragma unroll
    for (int r = 0; r < 4; ++r) {
      float s1 = acc[mt][0][r] + acc[mt][1][r];
      float s2 = acc[mt][0][r] * acc[mt][0][r] + acc[mt][1][r] * acc[mt][1][r];
#pragma unroll
      for (int o = 8; o >= 1; o >>= 1) {
        s1 += __shfl_xor(s1, o, 64);
        s2 += __shfl_xor(s2, o, 64);
      }
      if (l15 == 0) {
        const int c = c0 + wr * 32 + mt * 16 + 4 * h + r;
        partials[(size_t)c * 256 + slab] = s1;
        partials[65536 + (size_t)c * 256 + slab] = s2;
      }
    }
}

// ---------------------------------------------------------------------------
__global__ __launch_bounds__(256) void bn_reduce_kernel(
    const float* __restrict__ partials, float* __restrict__ stats) {
  const int c = blockIdx.x;
  const int tid = threadIdx.x;
  float s1 = partials[(size_t)c * 256 + tid];
  float s2 = partials[65536 + (size_t)c * 256 + tid];
  s1 = waveSum(s1);
  s2 = waveSum(s2);
  __shared__ float r1[4], r2[4];
  if ((tid & 63) == 0) { r1[tid >> 6] = s1; r2[tid >> 6] = s2; }
  __syncthreads();
  if (tid == 0) {
    float S = r1[0] + r1[1] + r1[2] + r1[3];
    float S2 = r2[0] + r2[1] + r2[2] + r2[3];
    const float invM = 1.f / (float)(Bn * Nn);
    float mean = S * invM;
    float var = S2 * invM - mean * mean;
    stats[c] = mean;
    stats[Cc + c] = rsqrtf(var + BN_EPS);
  }
}

__global__ __launch_bounds__(256) void bn_apply_kernel(
    const u16* __restrict__ proj, const float* __restrict__ stats,
    const float* __restrict__ gamma, const float* __restrict__ beta,
    float* __restrict__ out) {
  const int idx = blockIdx.x * 256 + threadIdx.x;
  const int flat = idx << 2;
  const int c = (flat >> 10) & (Cc - 1);
  us4 v = reinterpret_cast<const us4*>(proj)[idx];
  const float mean = stats[c];
  const float sc = stats[Cc + c] * gamma[c];
  const float sh = beta[c];
  float4 o;
  o.x = fmaxf((bf2f(v[0]) - mean) * sc + sh, 0.f);
  o.y = fmaxf((bf2f(v[1]) - mean) * sc + sh, 0.f);
  o.z = fmaxf((bf2f(v[2]) - mean) * sc + sh, 0.f);
  o.w = fmaxf((bf2f(v[3]) - mean) * sc + sh, 0.f);
  reinterpret_cast<float4*>(out)[idx] = o;
}

// ---------------------------------------------------------------------------
extern "C" void kernel_launch(void* const* d_in, const int* in_sizes, int n_in,
                              void* d_out, int out_size, void* d_ws, size_t ws_size,
                              hipStream_t stream) {
  const float* x = (const float*)d_in[0];
  const float* w_qkv = (const float*)d_in[1];
  const float* head_scale = (const float*)d_in[2];
  const float* w_out = (const float*)d_in[3];
  const float* gamma = (const float*)d_in[4];
  const float* beta = (const float*)d_in[5];
  float* out = (float*)d_out;

  char* w = (char*)d_ws;
  u16* qt = (u16*)(w + 0);                 // 8 MB
  u16* kt = (u16*)(w + 8388608);           // 8 MB
  u16* vt = (u16*)(w + 16777216);          // 8 MB
  u16* wA = (u16*)(w + 25165824);          // 7 MB (dead after qkv GEMM)
  u16* aout = (u16*)(w + 25165824);        // 8 MB (written post-GEMM, by attn)
  u16* xT = (u16*)(w + 33554432);          // 4.2 MB (dead after qkv GEMM)
  float* partials = (float*)(w + 33554432); // 512 KB, overlays dead xT
  u16* proj = (u16*)(w + 37748736);        // 4 MB bf16
  float* etab = (float*)(w + 71303168);    // 2 KB
  float* idn = (float*)(w + 71305216);     // 32 KB
  u16* zpage = (u16*)(w + 71337984);       // 512 B (zeroed by prep)
  float* stats = (float*)(w + 71860224);   // 2 KB
  u16* wB = (u16*)(w + 71862272);          // 256 KB

  prep_kernel<<<dim3(2120), dim3(256), 0, stream>>>(
      w_qkv, w_out, x, head_scale, wA, wB, xT, zpage, etab, idn);
  qkv_gemm_kernel<<<dim3(256), dim3(512), 0, stream>>>(wA, xT, zpage, idn, qt, kt, vt);
  attn_mfma_kernel<<<dim3(1024), dim3(256), 0, stream>>>(qt, kt, vt, head_scale, aout);
  conv1x1_mfma_kernel<<<dim3(512), dim3(256), 0, stream>>>(aout, wB, proj, partials);
  bn_reduce_kernel<<<dim3(Cc), dim3(256), 0, stream>>>(partials, stats);
  bn_apply_kernel<<<dim3((Bn * Cc * Nn / 4) / 256), dim3(256), 0, stream>>>(proj, stats, gamma, beta, out);
}

// Round 17
// 116.154 us; speedup vs baseline: 1.0127x; 1.0127x over previous
//
#include <hip/hip_runtime.h>
#include <math.h>

#define SMOOTH 1e-4f
#define BN_EPS 1e-5f

constexpr int Bn = 8;
constexpr int Cc = 256;
constexpr int Nn = 1024;   // H*W
constexpr int G = 8;       // heads
constexpr int INNER = 512;
constexpr int OC = 1536;   // 3*INNER
constexpr int KK = 2304;   // 9*256 im2col K

typedef unsigned short u16;
typedef __bf16 bf16x8 __attribute__((ext_vector_type(8)));
typedef float f32x4 __attribute__((ext_vector_type(4)));
typedef unsigned short us8 __attribute__((ext_vector_type(8)));
typedef unsigned short us4 __attribute__((ext_vector_type(4)));

__device__ __forceinline__ u16 f2bf(float f) {
  unsigned int u = __float_as_uint(f);
  unsigned int r = (u + 0x7fffu + ((u >> 16) & 1u)) >> 16;
  return (u16)r;
}
__device__ __forceinline__ float bf2f(u16 u) {
  return __uint_as_float(((unsigned int)u) << 16);
}

__device__ __forceinline__ float waveSum(float v) {
#pragma unroll
  for (int off = 32; off > 0; off >>= 1) v += __shfl_xor(v, off, 64);
  return v;
}

__device__ __forceinline__ void gl16(const u16* g, u16* l) {
  __builtin_amdgcn_global_load_lds(
      (const __attribute__((address_space(1))) unsigned int*)g,
      (__attribute__((address_space(3))) unsigned int*)l, 16, 0, 0);
}

__device__ __forceinline__ bf16x8 ld8(const u16* p) {
  return __builtin_bit_cast(bf16x8, *reinterpret_cast<const us8*>(p));
}

// raw barrier with compiler fences (no vmcnt/lgkm drain)
__device__ __forceinline__ void barrier_raw() {
  asm volatile("" ::: "memory");
  __builtin_amdgcn_s_barrier();
  asm volatile("" ::: "memory");
  __builtin_amdgcn_sched_barrier(0);
}

// swizzled LDS fragment read: rows of 64 u16, u16idx ^ ((row&7)<<3)
__device__ __forceinline__ bf16x8 ldfrag(const u16* base, int row, int col) {
  int idx = (row * 64 + col) ^ ((row & 7) << 3);
  return ld8(base + idx);
}

// ---------------------------------------------------------------------------
// merged prep: [0,1536) wconv | [1536,1600) wout repack (+zpage init) |
// [1600,2112) x->xT bf16 transpose | [2112,2120) pbtab. (unchanged)
// ---------------------------------------------------------------------------
__global__ __launch_bounds__(256) void prep_kernel(
    const float* __restrict__ wq, const float* __restrict__ wout,
    const float* __restrict__ x, const float* __restrict__ head_scale,
    u16* __restrict__ wA, u16* __restrict__ wB, u16* __restrict__ xT,
    u16* __restrict__ zpage, float* __restrict__ etab,
    float* __restrict__ idn) {
  __shared__ __align__(16) char smraw[9216];
  const int bid = blockIdx.x;
  const int tid = threadIdx.x;

  if (bid < 1536) {  // ---- wconv: wA[oc][tap*256+ic] ----
    float* sw = (float*)smraw;
    const int oc = bid;
    for (int i = tid; i < KK; i += 256) sw[i] = wq[(size_t)oc * KK + i];
    __syncthreads();
#pragma unroll
    for (int j = 0; j < 2; ++j) {
      int c8 = tid + j * 256;
      if (c8 < KK / 8) {
        us8 v;
#pragma unroll
        for (int e = 0; e < 8; ++e) {
          int k = c8 * 8 + e;
          int tap = k >> 8, ic = k & 255;
          v[e] = f2bf(sw[ic * 9 + tap]);
        }
        *reinterpret_cast<us8*>(wA + (size_t)oc * KK + c8 * 8) = v;
      }
    }
  } else if (bid < 1600) {  // ---- wout repack (+ zero page, 512 B) ----
    const int idx = (bid - 1536) * 256 + tid;
    const float4 a = reinterpret_cast<const float4*>(wout)[idx * 2];
    const float4 b = reinterpret_cast<const float4*>(wout)[idx * 2 + 1];
    us8 v;
    v[0] = f2bf(a.x); v[1] = f2bf(a.y); v[2] = f2bf(a.z); v[3] = f2bf(a.w);
    v[4] = f2bf(b.x); v[5] = f2bf(b.y); v[6] = f2bf(b.z); v[7] = f2bf(b.w);
    reinterpret_cast<us8*>(wB)[idx] = v;
    if (bid == 1536) zpage[tid] = 0;
  } else if (bid < 2112) {  // ---- x [b][ic][n] f32 -> xT [b][pix][ic] bf16 ----
    u16* sxt = (u16*)smraw;  // [32 px][136] u16
    const int lb = bid - 1600;
    const int b = lb >> 6;
    const int nt = (lb >> 1) & 31;
    const int icc = lb & 1;
    const int n0 = nt * 32;
    const int ic0 = icc * 128;
    const float* xb = x + (size_t)b * Cc * Nn;
    {
      const int px = tid & 31;
      const int ic8 = tid >> 5;
#pragma unroll
      for (int i2 = 0; i2 < 16; ++i2) {
        const int ic = ic8 * 16 + i2;
        sxt[px * 136 + ic] = f2bf(xb[(size_t)(ic0 + ic) * Nn + n0 + px]);
      }
    }
    __syncthreads();
    const int c8 = tid & 7;
    const int px = tid >> 3;
    u16* dst = xT + (((size_t)b * 1024 + n0 + px) * 256) + ic0 + c8 * 8;
#pragma unroll
    for (int c32 = 0; c32 < 2; ++c32)
      *reinterpret_cast<us8*>(dst + c32 * 64) =
          *reinterpret_cast<const us8*>(sxt + px * 136 + c32 * 64 + c8 * 8);
  } else {  // ---- pbtab ----
    float* et = (float*)smraw;
    float* rsum = (float*)smraw + 64;
    const int g = bid - 2112;
    const float hs = head_scale[g];
    const float sg = 1.f / (1.f + __expf(-hs));
    const float s = sg * (0.4f - 0.003f) + 0.003f;
    const float sf = 1.f / (2.f * s * s);
    if (tid < 64) {
      float v = 0.f;
      if (tid < 63) {
        float d = (float)(tid - 31) * (1.f / 32.f);
        v = __expf(-sf * d * d);
      }
      et[tid] = v;
      etab[g * 64 + tid] = v;
    }
    __syncthreads();
    if (tid < 32) {
      float sum = 0.f;
#pragma unroll
      for (int ym = 0; ym < 32; ++ym) sum += et[tid - ym + 31];
      rsum[tid] = sum;
    }
    __syncthreads();
    for (int i = tid; i < 1024; i += 256)
      idn[g * 1024 + i] = 1.f / (rsum[i >> 5] * rsum[i & 31]);
  }
}

// ---------------------------------------------------------------------------
// qkv implicit GEMM (unchanged). grid = 256, XCD-swizzled.
// ---------------------------------------------------------------------------
__global__ __launch_bounds__(512, 1) void qkv_gemm_kernel(
    const u16* __restrict__ wA, const u16* __restrict__ xT,
    const u16* __restrict__ zpage, const float* __restrict__ idn,
    u16* __restrict__ qt, u16* __restrict__ ktp, u16* __restrict__ vt) {
  const int tid = threadIdx.x;
  const int lane = tid & 63;
  const int wv = tid >> 6;
  const int wm = wv >> 2, wn = wv & 3;
  const int h = lane >> 4, l15 = lane & 15;
  const int wgid = ((int)blockIdx.x & 7) * 32 + ((int)blockIdx.x >> 3);
  const int bm = wgid & 7;
  const int bn = wgid >> 3;
  const int m0 = bm * 192;

  __shared__ __align__(16) u16 smem[57344];

  const int arow = tid >> 3;
  const int aslot = (tid & 7) ^ (arow & 7);
  const u16* gA0 = wA + (size_t)(m0 + arow) * KK + aslot * 8;
  const int bslot8 = ((tid & 3) ^ (((tid >> 2) & 3) ^ ((tid >> 4) & 3))) * 8;
  const int pimgBase = ((bn & 3) << 8) + (tid >> 2);
  const u16* xTb = xT + (size_t)(bn >> 2) * (1024 * 256);

  auto mkSrc = [&](int tap, int pass) -> const u16* {
    const int dyq = (tap * 11) >> 5;
    const int ddx = tap - 3 * dyq - 1;
    const int ddy = dyq - 1;
    const int pimg = pimgBase + pass * 128;
    const int sx = (pimg & 31) + ddx;
    const int sy = (pimg >> 5) + ddy;
    if (((unsigned)sx < 32u) && ((unsigned)sy < 32u))
      return xTb + (size_t)(pimg + ddx + ddy * 32) * 256 + bslot8;
    return zpage;
  };
  const u16* srcB0 = mkSrc(0, 0);
  const u16* srcB1 = mkSrc(0, 1);
  int koff = 0;

  const int aX = l15 & 7;
  const int bX = (l15 & 3) ^ ((l15 >> 2) & 3);
  const u16* aBase = smem + (wm * 96 + l15) * 64;
  const u16* bBase = smem + 12288 + (wn * 64 + l15) * 32;
  const int slA0 = (h ^ aX) * 8;
  const int slA1 = ((4 + h) ^ aX) * 8;
  const int slB = (h ^ bX) * 8;

  f32x4 acc[6][4];
#pragma unroll
  for (int i = 0; i < 6; ++i)
#pragma unroll
    for (int j = 0; j < 4; ++j) acc[i][j] = (f32x4){0.f, 0.f, 0.f, 0.f};

  auto STAGE_A = [&](int pass, int dbuf, int kti) {
    gl16(gA0 + (size_t)pass * 64 * KK + kti * 64,
         smem + dbuf + pass * 4096 + tid * 8);
  };
  auto STAGE_B = [&](int kap, int pass, int dbuf) {
    gl16((pass ? srcB1 : srcB0) + koff + kap * 32,
         smem + dbuf + 12288 + kap * 8192 + pass * 4096 + tid * 8);
  };

  STAGE_A(0, 0, 0); STAGE_A(1, 0, 0); STAGE_A(2, 0, 0);
  STAGE_B(0, 0, 0); STAGE_B(0, 1, 0);
  STAGE_B(1, 0, 0); STAGE_B(1, 1, 0);
  asm volatile("s_waitcnt vmcnt(2)" ::: "memory");
  barrier_raw();

  bf16x8 af[3], bf[4];
#pragma unroll 1
  for (int kt = 0; kt < 36; ++kt) {
    const int buf = (kt & 1) * 28672;
    const int nbuf = 28672 - buf;
    const bool more = (kt < 35);

    if (more && (kt & 3) == 3) {
      const int ntap = (kt + 1) >> 2;
      srcB0 = mkSrc(ntap, 0);
      srcB1 = mkSrc(ntap, 1);
    }
    koff = ((kt + 1) & 3) << 6;

    // ---- P1 ----
#pragma unroll
    for (int ni = 0; ni < 4; ++ni) bf[ni] = ld8(bBase + buf + ni * 512 + slB);
#pragma unroll
    for (int q = 0; q < 3; ++q) af[q] = ld8(aBase + buf + q * 1024 + slA0);
    if (more) { STAGE_A(0, nbuf, kt + 1); STAGE_A(1, nbuf, kt + 1); }
    barrier_raw();
    __builtin_amdgcn_s_setprio(1);
#pragma unroll
    for (int q = 0; q < 3; ++q)
#pragma unroll
      for (int ni = 0; ni < 4; ++ni)
        acc[q][ni] = __builtin_amdgcn_mfma_f32_16x16x32_bf16(af[q], bf[ni], acc[q][ni], 0, 0, 0);
    __builtin_amdgcn_s_setprio(0);

    // ---- P2 ----
#pragma unroll
    for (int q = 0; q < 3; ++q) af[q] = ld8(aBase + buf + (3 + q) * 1024 + slA0);
    if (more) {
      STAGE_A(2, nbuf, kt + 1); STAGE_B(0, 0, nbuf);
      asm volatile("s_waitcnt vmcnt(4)" ::: "memory");
    } else {
      asm volatile("s_waitcnt vmcnt(0)" ::: "memory");
    }
    barrier_raw();
    __builtin_amdgcn_s_setprio(1);
#pragma unroll
    for (int q = 0; q < 3; ++q)
#pragma unroll
      for (int ni = 0; ni < 4; ++ni)
        acc[3 + q][ni] = __builtin_amdgcn_mfma_f32_16x16x32_bf16(af[q], bf[ni], acc[3 + q][ni], 0, 0, 0);
    __builtin_amdgcn_s_setprio(0);

    // ---- P3 ----
#pragma unroll
    for (int ni = 0; ni < 4; ++ni) bf[ni] = ld8(bBase + buf + 8192 + ni * 512 + slB);
#pragma unroll
    for (int q = 0; q < 3; ++q) af[q] = ld8(aBase + buf + q * 1024 + slA1);
    if (more) { STAGE_B(0, 1, nbuf); STAGE_B(1, 0, nbuf); }
    barrier_raw();
    __builtin_amdgcn_s_setprio(1);
#pragma unroll
    for (int q = 0; q < 3; ++q)
#pragma unroll
      for (int ni = 0; ni < 4; ++ni)
        acc[q][ni] = __builtin_amdgcn_mfma_f32_16x16x32_bf16(af[q], bf[ni], acc[q][ni], 0, 0, 0);
    __builtin_amdgcn_s_setprio(0);

    // ---- P4 ----
#pragma unroll
    for (int q = 0; q < 3; ++q) af[q] = ld8(aBase + buf + (3 + q) * 1024 + slA1);
    if (more) {
      STAGE_B(1, 1, nbuf);
      asm volatile("s_waitcnt vmcnt(2)" ::: "memory");
    }
    barrier_raw();
    __builtin_amdgcn_s_setprio(1);
#pragma unroll
    for (int q = 0; q < 3; ++q)
#pragma unroll
      for (int ni = 0; ni < 4; ++ni)
        acc[3 + q][ni] = __builtin_amdgcn_mfma_f32_16x16x32_bf16(af[q], bf[ni], acc[3 + q][ni], 0, 0, 0);
    __builtin_amdgcn_s_setprio(0);
  }

  const int b = bn >> 2;
  const int nimgBase = (bn & 3) * 256 + wn * 64;
  float ssF[4], ssH[4];
#pragma unroll
  for (int ni = 0; ni < 4; ++ni) {
    float sF = 0.f, sH = 0.f;
#pragma unroll
    for (int m4 = 0; m4 < 6; ++m4) {
      float s = 0.f;
#pragma unroll
      for (int r = 0; r < 4; ++r) s += acc[m4][ni][r] * acc[m4][ni][r];
      const bool isFull = (wm == 0) ? (m4 < 4) : (m4 >= 2);
      if (isFull) sF += s; else sH += s;
    }
    sF += __shfl_xor(sF, 16, 64); sF += __shfl_xor(sF, 32, 64);
    sH += __shfl_xor(sH, 16, 64); sH += __shfl_xor(sH, 32, 64);
    ssF[ni] = sF; ssH[ni] = sH;
  }
  float* xch = (float*)smem;
  if (h == 0) {
#pragma unroll
    for (int ni = 0; ni < 4; ++ni)
      xch[((wm * 4 + wn) * 4 + ni) * 16 + l15] = ssH[ni];
  }
  __syncthreads();
#pragma unroll
  for (int ni = 0; ni < 4; ++ni)
    ssH[ni] += xch[(((1 - wm) * 4 + wn) * 4 + ni) * 16 + l15];

  const int headF = (wm == 0) ? 3 * bm : 3 * bm + 2;
  const int headH = 3 * bm + 1;
  const int secF = headF >> 3, gF = headF & 7;
  const int secH = headH >> 3, gH = headH & 7;
  float rsF[4], rsH[4];
#pragma unroll
  for (int ni = 0; ni < 4; ++ni) {
    const int nimg = nimgBase + ni * 16 + l15;
    float rf = rsqrtf(ssF[ni] + SMOOTH);
    if (secF == 0) rf *= idn[gF * 1024 + nimg];
    rsF[ni] = rf;
    float rh = rsqrtf(ssH[ni] + SMOOTH);
    if (secH == 0) rh *= idn[gH * 1024 + nimg];
    rsH[ni] = rh;
  }
#pragma unroll
  for (int m4 = 0; m4 < 6; ++m4) {
    const bool isFull = (wm == 0) ? (m4 < 4) : (m4 >= 2);
    const int head = isFull ? headF : headH;
    const int sec = head >> 3, g = head & 7;
    const int d0 = isFull ? ((wm == 0) ? m4 * 16 : (m4 - 2) * 16)
                          : ((wm == 0) ? (m4 - 4) * 16 : 32 + m4 * 16);
    const size_t bg = (size_t)b * G + g;
    if (sec < 2) {
      u16* basep = (sec ? ktp : qt) + bg * 65536;
#pragma unroll
      for (int ni = 0; ni < 4; ++ni) {
        const float rs = isFull ? rsF[ni] : rsH[ni];
        const int nimg = nimgBase + ni * 16 + l15;
        us4 v;
        v[0] = f2bf(acc[m4][ni][0] * rs);
        v[1] = f2bf(acc[m4][ni][1] * rs);
        v[2] = f2bf(acc[m4][ni][2] * rs);
        v[3] = f2bf(acc[m4][ni][3] * rs);
        *reinterpret_cast<us4*>(basep + (size_t)nimg * 64 + d0 + 4 * h) = v;
      }
    } else {
      u16* basep = vt + bg * 65536;
#pragma unroll
      for (int ni = 0; ni < 4; ++ni) {
        const int nimg = nimgBase + ni * 16 + l15;
#pragma unroll
        for (int r = 0; r < 4; ++r)
          basep[(size_t)(d0 + 4 * h + r) * 1024 + nimg] = f2bf(acc[m4][ni][r]);
      }
    }
  }
}

// ---------------------------------------------------------------------------
// MFMA attention (R14 structure, QBLK=128, etab-table pb) with Q loaded
// DIRECTLY global->registers (no sQ staging): LDS 48.25KB -> 3 blocks/CU.
// FIX vs R16: exv/ynr (etabL reads) moved AFTER the first __syncthreads
// (etabL is written by wave 0 only -- cross-wave RAW needs the barrier).
// ---------------------------------------------------------------------------
__global__ __launch_bounds__(256, 3) void attn_mfma_kernel(
    const u16* __restrict__ qt, const u16* __restrict__ ktp,
    const u16* __restrict__ vt, const float* __restrict__ etab,
    u16* __restrict__ aout) {
  const int tid = threadIdx.x;
  const int lane = tid & 63;
  const int wv = tid >> 6;
  const int h = lane >> 4;
  const int l15 = lane & 15;
  const int wgid = (blockIdx.x & 7) * 64 + (blockIdx.x >> 3);
  const int g = wgid >> 6;        // one g per XCD
  const int b = (wgid >> 3) & 7;
  const int nb = wgid & 7;

  __shared__ __align__(16) u16 smem[24576];  // 48 KB
  __shared__ float etabL[64];
  // K buf d: smem + d*4096 ; V buf d: smem + 8192 + d*4096
  u16* sP = smem + 16384 + wv * 2048;  // 32x64 per wave

  const size_t bg = (size_t)b * G + g;
  const u16* qg = qt + bg * 65536;
  const u16* kg = ktp + bg * 65536;
  const u16* vg = vt + bg * 65536;

  if (tid < 64) etabL[tid] = etab[g * 64 + tid];

  const int srow = tid >> 3;
  const int scol = ((tid & 7) ^ (srow & 7)) * 8;

  // prologue: stage K/V tile 0 into buf0
#pragma unroll
  for (int pass = 0; pass < 2; ++pass) {
    gl16(kg + (size_t)(pass * 32 + srow) * 64 + scol,
         smem + pass * 2048 + tid * 8);
    gl16(vg + (size_t)(pass * 32 + srow) * 1024 + scol,
         smem + 8192 + pass * 2048 + tid * 8);
  }

  const int col8 = h * 8;
  // Q fragments direct to registers (loop-invariant; A-operand rows n, k=d)
  bf16x8 aq[2][2];
#pragma unroll
  for (int kk = 0; kk < 2; ++kk)
#pragma unroll
    for (int ti = 0; ti < 2; ++ti)
      aq[kk][ti] = ld8(qg + (size_t)(nb * 128 + wv * 32 + ti * 16 + l15) * 64 +
                       kk * 32 + col8);

  f32x4 oacc[2][4];
#pragma unroll
  for (int ti = 0; ti < 2; ++ti)
#pragma unroll
    for (int dj = 0; dj < 4; ++dj) oacc[ti][dj] = (f32x4){0.f, 0.f, 0.f, 0.f};

  __syncthreads();  // K/V tile 0 landed + etabL visible to all waves

  // per-lane x-part of pb (reads etabL -- must be after the barrier)
  float exv[2][4][2];
  int ynr[2][4];
#pragma unroll
  for (int ti = 0; ti < 2; ++ti)
#pragma unroll
    for (int r = 0; r < 4; ++r) {
      int n = nb * 128 + wv * 32 + ti * 16 + 4 * h + r;
      int xn = n & 31;
      ynr[ti][r] = n >> 5;
      exv[ti][r][0] = etabL[xn - l15 + 31];
      exv[ti][r][1] = etabL[xn - l15 + 15];
    }

  for (int mt = 0; mt < 16; ++mt) {
    const u16* sKb = smem + (mt & 1) * 4096;
    const u16* sVb = smem + 8192 + (mt & 1) * 4096;
    if (mt < 15) {
      const int nt2 = mt + 1;
      const int d = nt2 & 1;
#pragma unroll
      for (int pass = 0; pass < 2; ++pass) {
        gl16(kg + (size_t)(nt2 * 64 + pass * 32 + srow) * 64 + scol,
             smem + d * 4096 + pass * 2048 + tid * 8);
        gl16(vg + (size_t)(pass * 32 + srow) * 1024 + nt2 * 64 + scol,
             smem + 8192 + d * 4096 + pass * 2048 + tid * 8);
      }
    }

    float eyv[2][4][2];
#pragma unroll
    for (int ti = 0; ti < 2; ++ti)
#pragma unroll
      for (int r = 0; r < 4; ++r) {
        eyv[ti][r][0] = etabL[ynr[ti][r] - 2 * mt + 31];
        eyv[ti][r][1] = etabL[ynr[ti][r] - 2 * mt + 30];
      }

    f32x4 sacc[2][4];
#pragma unroll
    for (int ti = 0; ti < 2; ++ti)
#pragma unroll
      for (int tj = 0; tj < 4; ++tj) sacc[ti][tj] = (f32x4){0.f, 0.f, 0.f, 0.f};
#pragma unroll
    for (int kk = 0; kk < 2; ++kk) {
#pragma unroll
      for (int tj = 0; tj < 4; ++tj) {
        bf16x8 bk = ldfrag(sKb, tj * 16 + l15, kk * 32 + col8);
        sacc[0][tj] = __builtin_amdgcn_mfma_f32_16x16x32_bf16(aq[kk][0], bk, sacc[0][tj], 0, 0, 0);
        sacc[1][tj] = __builtin_amdgcn_mfma_f32_16x16x32_bf16(aq[kk][1], bk, sacc[1][tj], 0, 0, 0);
      }
    }

#pragma unroll
    for (int tj = 0; tj < 4; ++tj) {
#pragma unroll
      for (int ti = 0; ti < 2; ++ti) {
#pragma unroll
        for (int r = 0; r < 4; ++r) {
          float wgt = sacc[ti][tj][r] * (eyv[ti][r][tj >> 1] * exv[ti][r][tj & 1]);
          int nl = ti * 16 + 4 * h + r;
          int pidx = (nl * 64 + tj * 16 + l15) ^ ((nl & 7) << 3);
          sP[pidx] = f2bf(wgt);
        }
      }
    }

#pragma unroll
    for (int km = 0; km < 2; ++km) {
      bf16x8 ap0 = ldfrag(sP, l15, km * 32 + col8);
      bf16x8 ap1 = ldfrag(sP, 16 + l15, km * 32 + col8);
#pragma unroll
      for (int dj = 0; dj < 4; ++dj) {
        bf16x8 bvv = ldfrag(sVb, dj * 16 + l15, km * 32 + col8);
        oacc[0][dj] = __builtin_amdgcn_mfma_f32_16x16x32_bf16(ap0, bvv, oacc[0][dj], 0, 0, 0);
        oacc[1][dj] = __builtin_amdgcn_mfma_f32_16x16x32_bf16(ap1, bvv, oacc[1][dj], 0, 0, 0);
      }
    }
    __syncthreads();
  }

  // output via swizzled LDS (K dbuf region now dead: 8192 u16 = 128x64)
  u16* sO = smem;
#pragma unroll
  for (int ti = 0; ti < 2; ++ti)
#pragma unroll
    for (int dj = 0; dj < 4; ++dj)
#pragma unroll
      for (int r = 0; r < 4; ++r) {
        int nl = wv * 32 + ti * 16 + 4 * h + r;
        int idx = (nl * 64 + dj * 16 + l15) ^ ((nl & 7) << 3);
        sO[idx] = f2bf(oacc[ti][dj][r]);
      }
  __syncthreads();
  {
    const int row = tid >> 1, c = (tid & 1) * 4;
    us8* dst = reinterpret_cast<us8*>(aout + (bg * 1024 + (size_t)nb * 128 + row) * 64);
#pragma unroll
    for (int k = 0; k < 4; ++k) {
      int idx = (row * 64 + (c + k) * 8) ^ ((row & 7) << 3);
      dst[c + k] = *reinterpret_cast<const us8*>(sO + idx);
    }
  }
}

// ---------------------------------------------------------------------------
// 1x1 conv as MFMA GEMM + fused deterministic BN partial stats. grid = 512.
// ---------------------------------------------------------------------------
__global__ __launch_bounds__(256, 4) void conv1x1_mfma_kernel(
    const u16* __restrict__ aout, const u16* __restrict__ wB,
    u16* __restrict__ proj, float* __restrict__ partials) {
  const int tid = threadIdx.x;
  const int lane = tid & 63;
  const int wv = tid >> 6;
  const int wr = wv >> 1, wc = wv & 1;
  const int h = lane >> 4, l15 = lane & 15;
  const int bm = blockIdx.x & 3;
  const int ntile = blockIdx.x >> 2;
  const int b = ntile >> 4;
  const int n0 = (ntile & 15) * 64;
  const int c0 = bm * 64;

  __shared__ __align__(16) u16 smem[16384];

  f32x4 acc[2][2];
#pragma unroll
  for (int i = 0; i < 2; ++i)
#pragma unroll
    for (int j = 0; j < 2; ++j) acc[i][j] = (f32x4){0.f, 0.f, 0.f, 0.f};

  const int srow = tid >> 3;
  const int scol = (tid & 7) * 8;

  auto STG = [&](int ks) {
    const int d = ks & 1;
#pragma unroll
    for (int pass = 0; pass < 2; ++pass) {
      gl16(wB + (size_t)(c0 + pass * 32 + srow) * 512 + ks * 64 + scol,
           smem + d * 4096 + pass * 2048 + tid * 8);
      gl16(aout + ((size_t)(b * G + ks) * 1024 + n0 + pass * 32 + srow) * 64 + scol,
           smem + 8192 + d * 4096 + pass * 2048 + tid * 8);
    }
  };

  STG(0);
  __syncthreads();
  for (int ks = 0; ks < 8; ++ks) {
    if (ks < 7) STG(ks + 1);
    const u16* sA = smem + (ks & 1) * 4096;
    const u16* sB = smem + 8192 + (ks & 1) * 4096;
#pragma unroll
    for (int kk = 0; kk < 2; ++kk) {
      bf16x8 af[2], bv[2];
#pragma unroll
      for (int mt = 0; mt < 2; ++mt)
        af[mt] = ld8(sA + (wr * 32 + mt * 16 + l15) * 64 + kk * 32 + h * 8);
#pragma unroll
      for (int nt = 0; nt < 2; ++nt)
        bv[nt] = ld8(sB + (wc * 32 + nt * 16 + l15) * 64 + kk * 32 + h * 8);
#pragma unroll
      for (int mt = 0; mt < 2; ++mt)
#pragma unroll
        for (int nt = 0; nt < 2; ++nt)
          acc[mt][nt] = __builtin_amdgcn_mfma_f32_16x16x32_bf16(af[mt], bv[nt], acc[mt][nt], 0, 0, 0);
    }
    __syncthreads();
  }

#pragma unroll
  for (int mt = 0; mt < 2; ++mt)
#pragma unroll
    for (int nt = 0; nt < 2; ++nt)
#pragma unroll
      for (int r = 0; r < 4; ++r) {
        const int c = c0 + wr * 32 + mt * 16 + 4 * h + r;
        const int n = n0 + wc * 32 + nt * 16 + l15;
        proj[((size_t)b * Cc + c) * Nn + n] = f2bf(acc[mt][nt][r]);
      }

  const int slab = ((b * 16 + (ntile & 15)) << 1) + wc;
#pragma unroll
  for (int mt = 0; mt < 2; ++mt)
#pragma unroll
    for (int r = 0; r < 4; ++r) {
      float s1 = acc[mt][0][r] + acc[mt][1][r];
      float s2 = acc[mt][0][r] * acc[mt][0][r] + acc[mt][1][r] * acc[mt][1][r];
#pragma unroll
      for (int o = 8; o >= 1; o >>= 1) {
        s1 += __shfl_xor(s1, o, 64);
        s2 += __shfl_xor(s2, o, 64);
      }
      if (l15 == 0) {
        const int c = c0 + wr * 32 + mt * 16 + 4 * h + r;
        partials[(size_t)c * 256 + slab] = s1;
        partials[65536 + (size_t)c * 256 + slab] = s2;
      }
    }
}

// ---------------------------------------------------------------------------
__global__ __launch_bounds__(256) void bn_reduce_kernel(
    const float* __restrict__ partials, float* __restrict__ stats) {
  const int c = blockIdx.x;
  const int tid = threadIdx.x;
  float s1 = partials[(size_t)c * 256 + tid];
  float s2 = partials[65536 + (size_t)c * 256 + tid];
  s1 = waveSum(s1);
  s2 = waveSum(s2);
  __shared__ float r1[4], r2[4];
  if ((tid & 63) == 0) { r1[tid >> 6] = s1; r2[tid >> 6] = s2; }
  __syncthreads();
  if (tid == 0) {
    float S = r1[0] + r1[1] + r1[2] + r1[3];
    float S2 = r2[0] + r2[1] + r2[2] + r2[3];
    const float invM = 1.f / (float)(Bn * Nn);
    float mean = S * invM;
    float var = S2 * invM - mean * mean;
    stats[c] = mean;
    stats[Cc + c] = rsqrtf(var + BN_EPS);
  }
}

__global__ __launch_bounds__(256) void bn_apply_kernel(
    const u16* __restrict__ proj, const float* __restrict__ stats,
    const float* __restrict__ gamma, const float* __restrict__ beta,
    float* __restrict__ out) {
  const int idx = blockIdx.x * 256 + threadIdx.x;
  const int flat = idx << 2;
  const int c = (flat >> 10) & (Cc - 1);
  us4 v = reinterpret_cast<const us4*>(proj)[idx];
  const float mean = stats[c];
  const float sc = stats[Cc + c] * gamma[c];
  const float sh = beta[c];
  float4 o;
  o.x = fmaxf((bf2f(v[0]) - mean) * sc + sh, 0.f);
  o.y = fmaxf((bf2f(v[1]) - mean) * sc + sh, 0.f);
  o.z = fmaxf((bf2f(v[2]) - mean) * sc + sh, 0.f);
  o.w = fmaxf((bf2f(v[3]) - mean) * sc + sh, 0.f);
  reinterpret_cast<float4*>(out)[idx] = o;
}

// ---------------------------------------------------------------------------
extern "C" void kernel_launch(void* const* d_in, const int* in_sizes, int n_in,
                              void* d_out, int out_size, void* d_ws, size_t ws_size,
                              hipStream_t stream) {
  const float* x = (const float*)d_in[0];
  const float* w_qkv = (const float*)d_in[1];
  const float* head_scale = (const float*)d_in[2];
  const float* w_out = (const float*)d_in[3];
  const float* gamma = (const float*)d_in[4];
  const float* beta = (const float*)d_in[5];
  float* out = (float*)d_out;

  char* w = (char*)d_ws;
  u16* qt = (u16*)(w + 0);                 // 8 MB
  u16* kt = (u16*)(w + 8388608);           // 8 MB
  u16* vt = (u16*)(w + 16777216);          // 8 MB
  u16* wA = (u16*)(w + 25165824);          // 7 MB (dead after qkv GEMM)
  u16* aout = (u16*)(w + 25165824);        // 8 MB (written post-GEMM, by attn)
  u16* xT = (u16*)(w + 33554432);          // 4.2 MB (dead after qkv GEMM)
  float* partials = (float*)(w + 33554432); // 512 KB, overlays dead xT
  u16* proj = (u16*)(w + 37748736);        // 4 MB bf16
  float* etab = (float*)(w + 71303168);    // 2 KB
  float* idn = (float*)(w + 71305216);     // 32 KB
  u16* zpage = (u16*)(w + 71337984);       // 512 B (zeroed by prep)
  float* stats = (float*)(w + 71860224);   // 2 KB
  u16* wB = (u16*)(w + 71862272);          // 256 KB

  prep_kernel<<<dim3(2120), dim3(256), 0, stream>>>(
      w_qkv, w_out, x, head_scale, wA, wB, xT, zpage, etab, idn);
  qkv_gemm_kernel<<<dim3(256), dim3(512), 0, stream>>>(wA, xT, zpage, idn, qt, kt, vt);
  attn_mfma_kernel<<<dim3(512), dim3(256), 0, stream>>>(qt, kt, vt, etab, aout);
  conv1x1_mfma_kernel<<<dim3(512), dim3(256), 0, stream>>>(aout, wB, proj, partials);
  bn_reduce_kernel<<<dim3(Cc), dim3(256), 0, stream>>>(partials, stats);
  bn_apply_kernel<<<dim3((Bn * Cc * Nn / 4) / 256), dim3(256), 0, stream>>>(proj, stats, gamma, beta, out);
}

// Round 18
// 113.426 us; speedup vs baseline: 1.0371x; 1.0240x over previous
//
#include <hip/hip_runtime.h>
#include <math.h>

#define SMOOTH 1e-4f
#define BN_EPS 1e-5f

constexpr int Bn = 8;
constexpr int Cc = 256;
constexpr int Nn = 1024;   // H*W
constexpr int G = 8;       // heads
constexpr int INNER = 512;
constexpr int OC = 1536;   // 3*INNER
constexpr int KK = 2304;   // 9*256 im2col K

typedef unsigned short u16;
typedef __bf16 bf16x8 __attribute__((ext_vector_type(8)));
typedef float f32x4 __attribute__((ext_vector_type(4)));
typedef unsigned short us8 __attribute__((ext_vector_type(8)));
typedef unsigned short us4 __attribute__((ext_vector_type(4)));

__device__ __forceinline__ u16 f2bf(float f) {
  unsigned int u = __float_as_uint(f);
  unsigned int r = (u + 0x7fffu + ((u >> 16) & 1u)) >> 16;
  return (u16)r;
}
__device__ __forceinline__ float bf2f(u16 u) {
  return __uint_as_float(((unsigned int)u) << 16);
}

__device__ __forceinline__ float waveSum(float v) {
#pragma unroll
  for (int off = 32; off > 0; off >>= 1) v += __shfl_xor(v, off, 64);
  return v;
}

__device__ __forceinline__ void gl16(const u16* g, u16* l) {
  __builtin_amdgcn_global_load_lds(
      (const __attribute__((address_space(1))) unsigned int*)g,
      (__attribute__((address_space(3))) unsigned int*)l, 16, 0, 0);
}

__device__ __forceinline__ bf16x8 ld8(const u16* p) {
  return __builtin_bit_cast(bf16x8, *reinterpret_cast<const us8*>(p));
}

// raw barrier with compiler fences (no vmcnt/lgkm drain)
__device__ __forceinline__ void barrier_raw() {
  asm volatile("" ::: "memory");
  __builtin_amdgcn_s_barrier();
  asm volatile("" ::: "memory");
  __builtin_amdgcn_sched_barrier(0);
}

// swizzled LDS fragment read: rows of 64 u16, u16idx ^ ((row&7)<<3)
__device__ __forceinline__ bf16x8 ldfrag(const u16* base, int row, int col) {
  int idx = (row * 64 + col) ^ ((row & 7) << 3);
  return ld8(base + idx);
}

// ---------------------------------------------------------------------------
// merged prep: [0,1536) wconv | [1536,1600) wout repack (+zpage init) |
// [1600,2112) x->xT bf16 transpose | [2112,2120) pbtab. (unchanged)
// ---------------------------------------------------------------------------
__global__ __launch_bounds__(256) void prep_kernel(
    const float* __restrict__ wq, const float* __restrict__ wout,
    const float* __restrict__ x, const float* __restrict__ head_scale,
    u16* __restrict__ wA, u16* __restrict__ wB, u16* __restrict__ xT,
    u16* __restrict__ zpage, float* __restrict__ etab,
    float* __restrict__ idn) {
  __shared__ __align__(16) char smraw[9216];
  const int bid = blockIdx.x;
  const int tid = threadIdx.x;

  if (bid < 1536) {  // ---- wconv: wA[oc][tap*256+ic] ----
    float* sw = (float*)smraw;
    const int oc = bid;
    for (int i = tid; i < KK; i += 256) sw[i] = wq[(size_t)oc * KK + i];
    __syncthreads();
#pragma unroll
    for (int j = 0; j < 2; ++j) {
      int c8 = tid + j * 256;
      if (c8 < KK / 8) {
        us8 v;
#pragma unroll
        for (int e = 0; e < 8; ++e) {
          int k = c8 * 8 + e;
          int tap = k >> 8, ic = k & 255;
          v[e] = f2bf(sw[ic * 9 + tap]);
        }
        *reinterpret_cast<us8*>(wA + (size_t)oc * KK + c8 * 8) = v;
      }
    }
  } else if (bid < 1600) {  // ---- wout repack (+ zero page, 512 B) ----
    const int idx = (bid - 1536) * 256 + tid;
    const float4 a = reinterpret_cast<const float4*>(wout)[idx * 2];
    const float4 b = reinterpret_cast<const float4*>(wout)[idx * 2 + 1];
    us8 v;
    v[0] = f2bf(a.x); v[1] = f2bf(a.y); v[2] = f2bf(a.z); v[3] = f2bf(a.w);
    v[4] = f2bf(b.x); v[5] = f2bf(b.y); v[6] = f2bf(b.z); v[7] = f2bf(b.w);
    reinterpret_cast<us8*>(wB)[idx] = v;
    if (bid == 1536) zpage[tid] = 0;
  } else if (bid < 2112) {  // ---- x [b][ic][n] f32 -> xT [b][pix][ic] bf16 ----
    u16* sxt = (u16*)smraw;  // [32 px][136] u16
    const int lb = bid - 1600;
    const int b = lb >> 6;
    const int nt = (lb >> 1) & 31;
    const int icc = lb & 1;
    const int n0 = nt * 32;
    const int ic0 = icc * 128;
    const float* xb = x + (size_t)b * Cc * Nn;
    {
      const int px = tid & 31;
      const int ic8 = tid >> 5;
#pragma unroll
      for (int i2 = 0; i2 < 16; ++i2) {
        const int ic = ic8 * 16 + i2;
        sxt[px * 136 + ic] = f2bf(xb[(size_t)(ic0 + ic) * Nn + n0 + px]);
      }
    }
    __syncthreads();
    const int c8 = tid & 7;
    const int px = tid >> 3;
    u16* dst = xT + (((size_t)b * 1024 + n0 + px) * 256) + ic0 + c8 * 8;
#pragma unroll
    for (int c32 = 0; c32 < 2; ++c32)
      *reinterpret_cast<us8*>(dst + c32 * 64) =
          *reinterpret_cast<const us8*>(sxt + px * 136 + c32 * 64 + c8 * 8);
  } else {  // ---- pbtab ----
    float* et = (float*)smraw;
    float* rsum = (float*)smraw + 64;
    const int g = bid - 2112;
    const float hs = head_scale[g];
    const float sg = 1.f / (1.f + __expf(-hs));
    const float s = sg * (0.4f - 0.003f) + 0.003f;
    const float sf = 1.f / (2.f * s * s);
    if (tid < 64) {
      float v = 0.f;
      if (tid < 63) {
        float d = (float)(tid - 31) * (1.f / 32.f);
        v = __expf(-sf * d * d);
      }
      et[tid] = v;
      etab[g * 64 + tid] = v;
    }
    __syncthreads();
    if (tid < 32) {
      float sum = 0.f;
#pragma unroll
      for (int ym = 0; ym < 32; ++ym) sum += et[tid - ym + 31];
      rsum[tid] = sum;
    }
    __syncthreads();
    for (int i = tid; i < 1024; i += 256)
      idn[g * 1024 + i] = 1.f / (rsum[i >> 5] * rsum[i & 31]);
  }
}

// ---------------------------------------------------------------------------
// qkv implicit GEMM (unchanged). grid = 256, XCD-swizzled.
// ---------------------------------------------------------------------------
__global__ __launch_bounds__(512, 1) void qkv_gemm_kernel(
    const u16* __restrict__ wA, const u16* __restrict__ xT,
    const u16* __restrict__ zpage, const float* __restrict__ idn,
    u16* __restrict__ qt, u16* __restrict__ ktp, u16* __restrict__ vt) {
  const int tid = threadIdx.x;
  const int lane = tid & 63;
  const int wv = tid >> 6;
  const int wm = wv >> 2, wn = wv & 3;
  const int h = lane >> 4, l15 = lane & 15;
  const int wgid = ((int)blockIdx.x & 7) * 32 + ((int)blockIdx.x >> 3);
  const int bm = wgid & 7;
  const int bn = wgid >> 3;
  const int m0 = bm * 192;

  __shared__ __align__(16) u16 smem[57344];

  const int arow = tid >> 3;
  const int aslot = (tid & 7) ^ (arow & 7);
  const u16* gA0 = wA + (size_t)(m0 + arow) * KK + aslot * 8;
  const int bslot8 = ((tid & 3) ^ (((tid >> 2) & 3) ^ ((tid >> 4) & 3))) * 8;
  const int pimgBase = ((bn & 3) << 8) + (tid >> 2);
  const u16* xTb = xT + (size_t)(bn >> 2) * (1024 * 256);

  auto mkSrc = [&](int tap, int pass) -> const u16* {
    const int dyq = (tap * 11) >> 5;
    const int ddx = tap - 3 * dyq - 1;
    const int ddy = dyq - 1;
    const int pimg = pimgBase + pass * 128;
    const int sx = (pimg & 31) + ddx;
    const int sy = (pimg >> 5) + ddy;
    if (((unsigned)sx < 32u) && ((unsigned)sy < 32u))
      return xTb + (size_t)(pimg + ddx + ddy * 32) * 256 + bslot8;
    return zpage;
  };
  const u16* srcB0 = mkSrc(0, 0);
  const u16* srcB1 = mkSrc(0, 1);
  int koff = 0;

  const int aX = l15 & 7;
  const int bX = (l15 & 3) ^ ((l15 >> 2) & 3);
  const u16* aBase = smem + (wm * 96 + l15) * 64;
  const u16* bBase = smem + 12288 + (wn * 64 + l15) * 32;
  const int slA0 = (h ^ aX) * 8;
  const int slA1 = ((4 + h) ^ aX) * 8;
  const int slB = (h ^ bX) * 8;

  f32x4 acc[6][4];
#pragma unroll
  for (int i = 0; i < 6; ++i)
#pragma unroll
    for (int j = 0; j < 4; ++j) acc[i][j] = (f32x4){0.f, 0.f, 0.f, 0.f};

  auto STAGE_A = [&](int pass, int dbuf, int kti) {
    gl16(gA0 + (size_t)pass * 64 * KK + kti * 64,
         smem + dbuf + pass * 4096 + tid * 8);
  };
  auto STAGE_B = [&](int kap, int pass, int dbuf) {
    gl16((pass ? srcB1 : srcB0) + koff + kap * 32,
         smem + dbuf + 12288 + kap * 8192 + pass * 4096 + tid * 8);
  };

  STAGE_A(0, 0, 0); STAGE_A(1, 0, 0); STAGE_A(2, 0, 0);
  STAGE_B(0, 0, 0); STAGE_B(0, 1, 0);
  STAGE_B(1, 0, 0); STAGE_B(1, 1, 0);
  asm volatile("s_waitcnt vmcnt(2)" ::: "memory");
  barrier_raw();

  bf16x8 af[3], bf[4];
#pragma unroll 1
  for (int kt = 0; kt < 36; ++kt) {
    const int buf = (kt & 1) * 28672;
    const int nbuf = 28672 - buf;
    const bool more = (kt < 35);

    if (more && (kt & 3) == 3) {
      const int ntap = (kt + 1) >> 2;
      srcB0 = mkSrc(ntap, 0);
      srcB1 = mkSrc(ntap, 1);
    }
    koff = ((kt + 1) & 3) << 6;

    // ---- P1 ----
#pragma unroll
    for (int ni = 0; ni < 4; ++ni) bf[ni] = ld8(bBase + buf + ni * 512 + slB);
#pragma unroll
    for (int q = 0; q < 3; ++q) af[q] = ld8(aBase + buf + q * 1024 + slA0);
    if (more) { STAGE_A(0, nbuf, kt + 1); STAGE_A(1, nbuf, kt + 1); }
    barrier_raw();
    __builtin_amdgcn_s_setprio(1);
#pragma unroll
    for (int q = 0; q < 3; ++q)
#pragma unroll
      for (int ni = 0; ni < 4; ++ni)
        acc[q][ni] = __builtin_amdgcn_mfma_f32_16x16x32_bf16(af[q], bf[ni], acc[q][ni], 0, 0, 0);
    __builtin_amdgcn_s_setprio(0);

    // ---- P2 ----
#pragma unroll
    for (int q = 0; q < 3; ++q) af[q] = ld8(aBase + buf + (3 + q) * 1024 + slA0);
    if (more) {
      STAGE_A(2, nbuf, kt + 1); STAGE_B(0, 0, nbuf);
      asm volatile("s_waitcnt vmcnt(4)" ::: "memory");
    } else {
      asm volatile("s_waitcnt vmcnt(0)" ::: "memory");
    }
    barrier_raw();
    __builtin_amdgcn_s_setprio(1);
#pragma unroll
    for (int q = 0; q < 3; ++q)
#pragma unroll
      for (int ni = 0; ni < 4; ++ni)
        acc[3 + q][ni] = __builtin_amdgcn_mfma_f32_16x16x32_bf16(af[q], bf[ni], acc[3 + q][ni], 0, 0, 0);
    __builtin_amdgcn_s_setprio(0);

    // ---- P3 ----
#pragma unroll
    for (int ni = 0; ni < 4; ++ni) bf[ni] = ld8(bBase + buf + 8192 + ni * 512 + slB);
#pragma unroll
    for (int q = 0; q < 3; ++q) af[q] = ld8(aBase + buf + q * 1024 + slA1);
    if (more) { STAGE_B(0, 1, nbuf); STAGE_B(1, 0, nbuf); }
    barrier_raw();
    __builtin_amdgcn_s_setprio(1);
#pragma unroll
    for (int q = 0; q < 3; ++q)
#pragma unroll
      for (int ni = 0; ni < 4; ++ni)
        acc[q][ni] = __builtin_amdgcn_mfma_f32_16x16x32_bf16(af[q], bf[ni], acc[q][ni], 0, 0, 0);
    __builtin_amdgcn_s_setprio(0);

    // ---- P4 ----
#pragma unroll
    for (int q = 0; q < 3; ++q) af[q] = ld8(aBase + buf + (3 + q) * 1024 + slA1);
    if (more) {
      STAGE_B(1, 1, nbuf);
      asm volatile("s_waitcnt vmcnt(2)" ::: "memory");
    }
    barrier_raw();
    __builtin_amdgcn_s_setprio(1);
#pragma unroll
    for (int q = 0; q < 3; ++q)
#pragma unroll
      for (int ni = 0; ni < 4; ++ni)
        acc[3 + q][ni] = __builtin_amdgcn_mfma_f32_16x16x32_bf16(af[q], bf[ni], acc[3 + q][ni], 0, 0, 0);
    __builtin_amdgcn_s_setprio(0);
  }

  const int b = bn >> 2;
  const int nimgBase = (bn & 3) * 256 + wn * 64;
  float ssF[4], ssH[4];
#pragma unroll
  for (int ni = 0; ni < 4; ++ni) {
    float sF = 0.f, sH = 0.f;
#pragma unroll
    for (int m4 = 0; m4 < 6; ++m4) {
      float s = 0.f;
#pragma unroll
      for (int r = 0; r < 4; ++r) s += acc[m4][ni][r] * acc[m4][ni][r];
      const bool isFull = (wm == 0) ? (m4 < 4) : (m4 >= 2);
      if (isFull) sF += s; else sH += s;
    }
    sF += __shfl_xor(sF, 16, 64); sF += __shfl_xor(sF, 32, 64);
    sH += __shfl_xor(sH, 16, 64); sH += __shfl_xor(sH, 32, 64);
    ssF[ni] = sF; ssH[ni] = sH;
  }
  float* xch = (float*)smem;
  if (h == 0) {
#pragma unroll
    for (int ni = 0; ni < 4; ++ni)
      xch[((wm * 4 + wn) * 4 + ni) * 16 + l15] = ssH[ni];
  }
  __syncthreads();
#pragma unroll
  for (int ni = 0; ni < 4; ++ni)
    ssH[ni] += xch[(((1 - wm) * 4 + wn) * 4 + ni) * 16 + l15];

  const int headF = (wm == 0) ? 3 * bm : 3 * bm + 2;
  const int headH = 3 * bm + 1;
  const int secF = headF >> 3, gF = headF & 7;
  const int secH = headH >> 3, gH = headH & 7;
  float rsF[4], rsH[4];
#pragma unroll
  for (int ni = 0; ni < 4; ++ni) {
    const int nimg = nimgBase + ni * 16 + l15;
    float rf = rsqrtf(ssF[ni] + SMOOTH);
    if (secF == 0) rf *= idn[gF * 1024 + nimg];
    rsF[ni] = rf;
    float rh = rsqrtf(ssH[ni] + SMOOTH);
    if (secH == 0) rh *= idn[gH * 1024 + nimg];
    rsH[ni] = rh;
  }
#pragma unroll
  for (int m4 = 0; m4 < 6; ++m4) {
    const bool isFull = (wm == 0) ? (m4 < 4) : (m4 >= 2);
    const int head = isFull ? headF : headH;
    const int sec = head >> 3, g = head & 7;
    const int d0 = isFull ? ((wm == 0) ? m4 * 16 : (m4 - 2) * 16)
                          : ((wm == 0) ? (m4 - 4) * 16 : 32 + m4 * 16);
    const size_t bg = (size_t)b * G + g;
    if (sec < 2) {
      u16* basep = (sec ? ktp : qt) + bg * 65536;
#pragma unroll
      for (int ni = 0; ni < 4; ++ni) {
        const float rs = isFull ? rsF[ni] : rsH[ni];
        const int nimg = nimgBase + ni * 16 + l15;
        us4 v;
        v[0] = f2bf(acc[m4][ni][0] * rs);
        v[1] = f2bf(acc[m4][ni][1] * rs);
        v[2] = f2bf(acc[m4][ni][2] * rs);
        v[3] = f2bf(acc[m4][ni][3] * rs);
        *reinterpret_cast<us4*>(basep + (size_t)nimg * 64 + d0 + 4 * h) = v;
      }
    } else {
      u16* basep = vt + bg * 65536;
#pragma unroll
      for (int ni = 0; ni < 4; ++ni) {
        const int nimg = nimgBase + ni * 16 + l15;
#pragma unroll
        for (int r = 0; r < 4; ++r)
          basep[(size_t)(d0 + 4 * h + r) * 1024 + nimg] = f2bf(acc[m4][ni][r]);
      }
    }
  }
}

// ---------------------------------------------------------------------------
// MFMA attention (R14 known-good): QBLK=128, sQ LDS-staged, Q fragments
// hoisted after sync, K/V double-buffered, one __syncthreads per m-tile.
// LDS 64KB -> 2 blocks/CU. grid = 512, XCD-swizzled by head g.
// ---------------------------------------------------------------------------
__global__ __launch_bounds__(256, 2) void attn_mfma_kernel(
    const u16* __restrict__ qt, const u16* __restrict__ ktp,
    const u16* __restrict__ vt, const float* __restrict__ etab,
    u16* __restrict__ aout) {
  const int tid = threadIdx.x;
  const int lane = tid & 63;
  const int wv = tid >> 6;
  const int h = lane >> 4;
  const int l15 = lane & 15;
  const int wgid = (blockIdx.x & 7) * 64 + (blockIdx.x >> 3);
  const int g = wgid >> 6;
  const int b = (wgid >> 3) & 7;
  const int nb = wgid & 7;

  __shared__ __align__(16) u16 smem[32768];  // 64 KB
  __shared__ float etabL[64];
  u16* sQ = smem;
  u16* sP = smem + 24576 + wv * 2048;

  const size_t bg = (size_t)b * G + g;
  const u16* qg = qt + bg * 65536;
  const u16* kg = ktp + bg * 65536;
  const u16* vg = vt + bg * 65536;

  if (tid < 64) etabL[tid] = etab[g * 64 + tid];

  const int srow = tid >> 3;
  const int scol = ((tid & 7) ^ (srow & 7)) * 8;

#pragma unroll
  for (int pass = 0; pass < 4; ++pass)
    gl16(qg + (size_t)(nb * 128 + pass * 32 + srow) * 64 + scol,
         sQ + pass * 2048 + tid * 8);
#pragma unroll
  for (int pass = 0; pass < 2; ++pass) {
    gl16(kg + (size_t)(pass * 32 + srow) * 64 + scol,
         smem + 8192 + pass * 2048 + tid * 8);
    gl16(vg + (size_t)(pass * 32 + srow) * 1024 + scol,
         smem + 16384 + pass * 2048 + tid * 8);
  }
  __syncthreads();

  const int col8 = h * 8;

  // hoist Q fragments (loop-invariant across all 16 m-tiles)
  bf16x8 aq[2][2];
#pragma unroll
  for (int kk = 0; kk < 2; ++kk) {
    aq[kk][0] = ldfrag(sQ, wv * 32 + l15, kk * 32 + col8);
    aq[kk][1] = ldfrag(sQ, wv * 32 + 16 + l15, kk * 32 + col8);
  }

  float exv[2][4][2];
  int ynr[2][4];
#pragma unroll
  for (int ti = 0; ti < 2; ++ti)
#pragma unroll
    for (int r = 0; r < 4; ++r) {
      int n = nb * 128 + wv * 32 + ti * 16 + 4 * h + r;
      int xn = n & 31;
      ynr[ti][r] = n >> 5;
      exv[ti][r][0] = etabL[xn - l15 + 31];
      exv[ti][r][1] = etabL[xn - l15 + 15];
    }

  f32x4 oacc[2][4];
#pragma unroll
  for (int ti = 0; ti < 2; ++ti)
#pragma unroll
    for (int dj = 0; dj < 4; ++dj) oacc[ti][dj] = (f32x4){0.f, 0.f, 0.f, 0.f};

  for (int mt = 0; mt < 16; ++mt) {
    const u16* sKb = smem + 8192 + (mt & 1) * 4096;
    const u16* sVb = smem + 16384 + (mt & 1) * 4096;
    if (mt < 15) {
      const int nt2 = mt + 1;
      const int d = nt2 & 1;
#pragma unroll
      for (int pass = 0; pass < 2; ++pass) {
        gl16(kg + (size_t)(nt2 * 64 + pass * 32 + srow) * 64 + scol,
             smem + 8192 + d * 4096 + pass * 2048 + tid * 8);
        gl16(vg + (size_t)(pass * 32 + srow) * 1024 + nt2 * 64 + scol,
             smem + 16384 + d * 4096 + pass * 2048 + tid * 8);
      }
    }

    float eyv[2][4][2];
#pragma unroll
    for (int ti = 0; ti < 2; ++ti)
#pragma unroll
      for (int r = 0; r < 4; ++r) {
        eyv[ti][r][0] = etabL[ynr[ti][r] - 2 * mt + 31];
        eyv[ti][r][1] = etabL[ynr[ti][r] - 2 * mt + 30];
      }

    f32x4 sacc[2][4];
#pragma unroll
    for (int ti = 0; ti < 2; ++ti)
#pragma unroll
      for (int tj = 0; tj < 4; ++tj) sacc[ti][tj] = (f32x4){0.f, 0.f, 0.f, 0.f};
#pragma unroll
    for (int kk = 0; kk < 2; ++kk) {
#pragma unroll
      for (int tj = 0; tj < 4; ++tj) {
        bf16x8 bk = ldfrag(sKb, tj * 16 + l15, kk * 32 + col8);
        sacc[0][tj] = __builtin_amdgcn_mfma_f32_16x16x32_bf16(aq[kk][0], bk, sacc[0][tj], 0, 0, 0);
        sacc[1][tj] = __builtin_amdgcn_mfma_f32_16x16x32_bf16(aq[kk][1], bk, sacc[1][tj], 0, 0, 0);
      }
    }

#pragma unroll
    for (int tj = 0; tj < 4; ++tj) {
#pragma unroll
      for (int ti = 0; ti < 2; ++ti) {
#pragma unroll
        for (int r = 0; r < 4; ++r) {
          float wgt = sacc[ti][tj][r] * (eyv[ti][r][tj >> 1] * exv[ti][r][tj & 1]);
          int nl = ti * 16 + 4 * h + r;
          int pidx = (nl * 64 + tj * 16 + l15) ^ ((nl & 7) << 3);
          sP[pidx] = f2bf(wgt);
        }
      }
    }

#pragma unroll
    for (int km = 0; km < 2; ++km) {
      bf16x8 ap0 = ldfrag(sP, l15, km * 32 + col8);
      bf16x8 ap1 = ldfrag(sP, 16 + l15, km * 32 + col8);
#pragma unroll
      for (int dj = 0; dj < 4; ++dj) {
        bf16x8 bvv = ldfrag(sVb, dj * 16 + l15, km * 32 + col8);
        oacc[0][dj] = __builtin_amdgcn_mfma_f32_16x16x32_bf16(ap0, bvv, oacc[0][dj], 0, 0, 0);
        oacc[1][dj] = __builtin_amdgcn_mfma_f32_16x16x32_bf16(ap1, bvv, oacc[1][dj], 0, 0, 0);
      }
    }
    __syncthreads();
  }

  u16* sO = smem + 8192;
#pragma unroll
  for (int ti = 0; ti < 2; ++ti)
#pragma unroll
    for (int dj = 0; dj < 4; ++dj)
#pragma unroll
      for (int r = 0; r < 4; ++r) {
        int nl = wv * 32 + ti * 16 + 4 * h + r;
        int idx = (nl * 64 + dj * 16 + l15) ^ ((nl & 7) << 3);
        sO[idx] = f2bf(oacc[ti][dj][r]);
      }
  __syncthreads();
  {
    const int row = tid >> 1, c = (tid & 1) * 4;
    us8* dst = reinterpret_cast<us8*>(aout + (bg * 1024 + (size_t)nb * 128 + row) * 64);
#pragma unroll
    for (int k = 0; k < 4; ++k) {
      int idx = (row * 64 + (c + k) * 8) ^ ((row & 7) << 3);
      dst[c + k] = *reinterpret_cast<const us8*>(sO + idx);
    }
  }
}

// ---------------------------------------------------------------------------
// 1x1 conv as MFMA GEMM + fused deterministic BN partial stats. grid = 512.
// ---------------------------------------------------------------------------
__global__ __launch_bounds__(256, 4) void conv1x1_mfma_kernel(
    const u16* __restrict__ aout, const u16* __restrict__ wB,
    u16* __restrict__ proj, float* __restrict__ partials) {
  const int tid = threadIdx.x;
  const int lane = tid & 63;
  const int wv = tid >> 6;
  const int wr = wv >> 1, wc = wv & 1;
  const int h = lane >> 4, l15 = lane & 15;
  const int bm = blockIdx.x & 3;
  const int ntile = blockIdx.x >> 2;
  const int b = ntile >> 4;
  const int n0 = (ntile & 15) * 64;
  const int c0 = bm * 64;

  __shared__ __align__(16) u16 smem[16384];

  f32x4 acc[2][2];
#pragma unroll
  for (int i = 0; i < 2; ++i)
#pragma unroll
    for (int j = 0; j < 2; ++j) acc[i][j] = (f32x4){0.f, 0.f, 0.f, 0.f};

  const int srow = tid >> 3;
  const int scol = (tid & 7) * 8;

  auto STG = [&](int ks) {
    const int d = ks & 1;
#pragma unroll
    for (int pass = 0; pass < 2; ++pass) {
      gl16(wB + (size_t)(c0 + pass * 32 + srow) * 512 + ks * 64 + scol,
           smem + d * 4096 + pass * 2048 + tid * 8);
      gl16(aout + ((size_t)(b * G + ks) * 1024 + n0 + pass * 32 + srow) * 64 + scol,
           smem + 8192 + d * 4096 + pass * 2048 + tid * 8);
    }
  };

  STG(0);
  __syncthreads();
  for (int ks = 0; ks < 8; ++ks) {
    if (ks < 7) STG(ks + 1);
    const u16* sA = smem + (ks & 1) * 4096;
    const u16* sB = smem + 8192 + (ks & 1) * 4096;
#pragma unroll
    for (int kk = 0; kk < 2; ++kk) {
      bf16x8 af[2], bv[2];
#pragma unroll
      for (int mt = 0; mt < 2; ++mt)
        af[mt] = ld8(sA + (wr * 32 + mt * 16 + l15) * 64 + kk * 32 + h * 8);
#pragma unroll
      for (int nt = 0; nt < 2; ++nt)
        bv[nt] = ld8(sB + (wc * 32 + nt * 16 + l15) * 64 + kk * 32 + h * 8);
#pragma unroll
      for (int mt = 0; mt < 2; ++mt)
#pragma unroll
        for (int nt = 0; nt < 2; ++nt)
          acc[mt][nt] = __builtin_amdgcn_mfma_f32_16x16x32_bf16(af[mt], bv[nt], acc[mt][nt], 0, 0, 0);
    }
    __syncthreads();
  }

#pragma unroll
  for (int mt = 0; mt < 2; ++mt)
#pragma unroll
    for (int nt = 0; nt < 2; ++nt)
#pragma unroll
      for (int r = 0; r < 4; ++r) {
        const int c = c0 + wr * 32 + mt * 16 + 4 * h + r;
        const int n = n0 + wc * 32 + nt * 16 + l15;
        proj[((size_t)b * Cc + c) * Nn + n] = f2bf(acc[mt][nt][r]);
      }

  const int slab = ((b * 16 + (ntile & 15)) << 1) + wc;
#pragma unroll
  for (int mt = 0; mt < 2; ++mt)
#pragma unroll
    for (int r = 0; r < 4; ++r) {
      float s1 = acc[mt][0][r] + acc[mt][1][r];
      float s2 = acc[mt][0][r] * acc[mt][0][r] + acc[mt][1][r] * acc[mt][1][r];
#pragma unroll
      for (int o = 8; o >= 1; o >>= 1) {
        s1 += __shfl_xor(s1, o, 64);
        s2 += __shfl_xor(s2, o, 64);
      }
      if (l15 == 0) {
        const int c = c0 + wr * 32 + mt * 16 + 4 * h + r;
        partials[(size_t)c * 256 + slab] = s1;
        partials[65536 + (size_t)c * 256 + slab] = s2;
      }
    }
}

// ---------------------------------------------------------------------------
__global__ __launch_bounds__(256) void bn_reduce_kernel(
    const float* __restrict__ partials, float* __restrict__ stats) {
  const int c = blockIdx.x;
  const int tid = threadIdx.x;
  float s1 = partials[(size_t)c * 256 + tid];
  float s2 = partials[65536 + (size_t)c * 256 + tid];
  s1 = waveSum(s1);
  s2 = waveSum(s2);
  __shared__ float r1[4], r2[4];
  if ((tid & 63) == 0) { r1[tid >> 6] = s1; r2[tid >> 6] = s2; }
  __syncthreads();
  if (tid == 0) {
    float S = r1[0] + r1[1] + r1[2] + r1[3];
    float S2 = r2[0] + r2[1] + r2[2] + r2[3];
    const float invM = 1.f / (float)(Bn * Nn);
    float mean = S * invM;
    float var = S2 * invM - mean * mean;
    stats[c] = mean;
    stats[Cc + c] = rsqrtf(var + BN_EPS);
  }
}

__global__ __launch_bounds__(256) void bn_apply_kernel(
    const u16* __restrict__ proj, const float* __restrict__ stats,
    const float* __restrict__ gamma, const float* __restrict__ beta,
    float* __restrict__ out) {
  const int idx = blockIdx.x * 256 + threadIdx.x;
  const int flat = idx << 2;
  const int c = (flat >> 10) & (Cc - 1);
  us4 v = reinterpret_cast<const us4*>(proj)[idx];
  const float mean = stats[c];
  const float sc = stats[Cc + c] * gamma[c];
  const float sh = beta[c];
  float4 o;
  o.x = fmaxf((bf2f(v[0]) - mean) * sc + sh, 0.f);
  o.y = fmaxf((bf2f(v[1]) - mean) * sc + sh, 0.f);
  o.z = fmaxf((bf2f(v[2]) - mean) * sc + sh, 0.f);
  o.w = fmaxf((bf2f(v[3]) - mean) * sc + sh, 0.f);
  reinterpret_cast<float4*>(out)[idx] = o;
}

// ---------------------------------------------------------------------------
extern "C" void kernel_launch(void* const* d_in, const int* in_sizes, int n_in,
                              void* d_out, int out_size, void* d_ws, size_t ws_size,
                              hipStream_t stream) {
  const float* x = (const float*)d_in[0];
  const float* w_qkv = (const float*)d_in[1];
  const float* head_scale = (const float*)d_in[2];
  const float* w_out = (const float*)d_in[3];
  const float* gamma = (const float*)d_in[4];
  const float* beta = (const float*)d_in[5];
  float* out = (float*)d_out;

  char* w = (char*)d_ws;
  u16* qt = (u16*)(w + 0);                 // 8 MB
  u16* kt = (u16*)(w + 8388608);           // 8 MB
  u16* vt = (u16*)(w + 16777216);          // 8 MB
  u16* wA = (u16*)(w + 25165824);          // 7 MB (dead after qkv GEMM)
  u16* aout = (u16*)(w + 25165824);        // 8 MB (written post-GEMM, by attn)
  u16* xT = (u16*)(w + 33554432);          // 4.2 MB (dead after qkv GEMM)
  float* partials = (float*)(w + 33554432); // 512 KB, overlays dead xT
  u16* proj = (u16*)(w + 37748736);        // 4 MB bf16
  float* etab = (float*)(w + 71303168);    // 2 KB
  float* idn = (float*)(w + 71305216);     // 32 KB
  u16* zpage = (u16*)(w + 71337984);       // 512 B (zeroed by prep)
  float* stats = (float*)(w + 71860224);   // 2 KB
  u16* wB = (u16*)(w + 71862272);          // 256 KB

  prep_kernel<<<dim3(2120), dim3(256), 0, stream>>>(
      w_qkv, w_out, x, head_scale, wA, wB, xT, zpage, etab, idn);
  qkv_gemm_kernel<<<dim3(256), dim3(512), 0, stream>>>(wA, xT, zpage, idn, qt, kt, vt);
  attn_mfma_kernel<<<dim3(512), dim3(256), 0, stream>>>(qt, kt, vt, etab, aout);
  conv1x1_mfma_kernel<<<dim3(512), dim3(256), 0, stream>>>(aout, wB, proj, partials);
  bn_reduce_kernel<<<dim3(Cc), dim3(256), 0, stream>>>(partials, stats);
  bn_apply_kernel<<<dim3((Bn * Cc * Nn / 4) / 256), dim3(256), 0, stream>>>(proj, stats, gamma, beta, out);
}

// Round 19
// 112.318 us; speedup vs baseline: 1.0473x; 1.0099x over previous
//
#include <hip/hip_runtime.h>
#include <math.h>

#define SMOOTH 1e-4f
#define BN_EPS 1e-5f

constexpr int Bn = 8;
constexpr int Cc = 256;
constexpr int Nn = 1024;   // H*W
constexpr int G = 8;       // heads
constexpr int INNER = 512;
constexpr int OC = 1536;   // 3*INNER
constexpr int KK = 2304;   // 9*256 im2col K

typedef unsigned short u16;
typedef __bf16 bf16x8 __attribute__((ext_vector_type(8)));
typedef float f32x4 __attribute__((ext_vector_type(4)));
typedef unsigned short us8 __attribute__((ext_vector_type(8)));
typedef unsigned short us4 __attribute__((ext_vector_type(4)));

__device__ __forceinline__ u16 f2bf(float f) {
  unsigned int u = __float_as_uint(f);
  unsigned int r = (u + 0x7fffu + ((u >> 16) & 1u)) >> 16;
  return (u16)r;
}
__device__ __forceinline__ float bf2f(u16 u) {
  return __uint_as_float(((unsigned int)u) << 16);
}

__device__ __forceinline__ float waveSum(float v) {
#pragma unroll
  for (int off = 32; off > 0; off >>= 1) v += __shfl_xor(v, off, 64);
  return v;
}

__device__ __forceinline__ void gl16(const u16* g, u16* l) {
  __builtin_amdgcn_global_load_lds(
      (const __attribute__((address_space(1))) unsigned int*)g,
      (__attribute__((address_space(3))) unsigned int*)l, 16, 0, 0);
}

__device__ __forceinline__ bf16x8 ld8(const u16* p) {
  return __builtin_bit_cast(bf16x8, *reinterpret_cast<const us8*>(p));
}

// raw barrier with compiler fences (no vmcnt/lgkm drain)
__device__ __forceinline__ void barrier_raw() {
  asm volatile("" ::: "memory");
  __builtin_amdgcn_s_barrier();
  asm volatile("" ::: "memory");
  __builtin_amdgcn_sched_barrier(0);
}

// swizzled LDS fragment read: rows of 64 u16, u16idx ^ ((row&7)<<3)
__device__ __forceinline__ bf16x8 ldfrag(const u16* base, int row, int col) {
  int idx = (row * 64 + col) ^ ((row & 7) << 3);
  return ld8(base + idx);
}

// ---------------------------------------------------------------------------
// merged prep: [0,1536) wconv | [1536,1600) wout repack (+zpage init) |
// [1600,2112) x->xT bf16 transpose | [2112,2120) pbtab. (unchanged)
// ---------------------------------------------------------------------------
__global__ __launch_bounds__(256) void prep_kernel(
    const float* __restrict__ wq, const float* __restrict__ wout,
    const float* __restrict__ x, const float* __restrict__ head_scale,
    u16* __restrict__ wA, u16* __restrict__ wB, u16* __restrict__ xT,
    u16* __restrict__ zpage, float* __restrict__ etab,
    float* __restrict__ idn) {
  __shared__ __align__(16) char smraw[9216];
  const int bid = blockIdx.x;
  const int tid = threadIdx.x;

  if (bid < 1536) {  // ---- wconv: wA[oc][tap*256+ic] ----
    float* sw = (float*)smraw;
    const int oc = bid;
    for (int i = tid; i < KK; i += 256) sw[i] = wq[(size_t)oc * KK + i];
    __syncthreads();
#pragma unroll
    for (int j = 0; j < 2; ++j) {
      int c8 = tid + j * 256;
      if (c8 < KK / 8) {
        us8 v;
#pragma unroll
        for (int e = 0; e < 8; ++e) {
          int k = c8 * 8 + e;
          int tap = k >> 8, ic = k & 255;
          v[e] = f2bf(sw[ic * 9 + tap]);
        }
        *reinterpret_cast<us8*>(wA + (size_t)oc * KK + c8 * 8) = v;
      }
    }
  } else if (bid < 1600) {  // ---- wout repack (+ zero page, 512 B) ----
    const int idx = (bid - 1536) * 256 + tid;
    const float4 a = reinterpret_cast<const float4*>(wout)[idx * 2];
    const float4 b = reinterpret_cast<const float4*>(wout)[idx * 2 + 1];
    us8 v;
    v[0] = f2bf(a.x); v[1] = f2bf(a.y); v[2] = f2bf(a.z); v[3] = f2bf(a.w);
    v[4] = f2bf(b.x); v[5] = f2bf(b.y); v[6] = f2bf(b.z); v[7] = f2bf(b.w);
    reinterpret_cast<us8*>(wB)[idx] = v;
    if (bid == 1536) zpage[tid] = 0;
  } else if (bid < 2112) {  // ---- x [b][ic][n] f32 -> xT [b][pix][ic] bf16 ----
    u16* sxt = (u16*)smraw;  // [32 px][136] u16
    const int lb = bid - 1600;
    const int b = lb >> 6;
    const int nt = (lb >> 1) & 31;
    const int icc = lb & 1;
    const int n0 = nt * 32;
    const int ic0 = icc * 128;
    const float* xb = x + (size_t)b * Cc * Nn;
    {
      const int px = tid & 31;
      const int ic8 = tid >> 5;
#pragma unroll
      for (int i2 = 0; i2 < 16; ++i2) {
        const int ic = ic8 * 16 + i2;
        sxt[px * 136 + ic] = f2bf(xb[(size_t)(ic0 + ic) * Nn + n0 + px]);
      }
    }
    __syncthreads();
    const int c8 = tid & 7;
    const int px = tid >> 3;
    u16* dst = xT + (((size_t)b * 1024 + n0 + px) * 256) + ic0 + c8 * 8;
#pragma unroll
    for (int c32 = 0; c32 < 2; ++c32)
      *reinterpret_cast<us8*>(dst + c32 * 64) =
          *reinterpret_cast<const us8*>(sxt + px * 136 + c32 * 64 + c8 * 8);
  } else {  // ---- pbtab ----
    float* et = (float*)smraw;
    float* rsum = (float*)smraw + 64;
    const int g = bid - 2112;
    const float hs = head_scale[g];
    const float sg = 1.f / (1.f + __expf(-hs));
    const float s = sg * (0.4f - 0.003f) + 0.003f;
    const float sf = 1.f / (2.f * s * s);
    if (tid < 64) {
      float v = 0.f;
      if (tid < 63) {
        float d = (float)(tid - 31) * (1.f / 32.f);
        v = __expf(-sf * d * d);
      }
      et[tid] = v;
      etab[g * 64 + tid] = v;
    }
    __syncthreads();
    if (tid < 32) {
      float sum = 0.f;
#pragma unroll
      for (int ym = 0; ym < 32; ++ym) sum += et[tid - ym + 31];
      rsum[tid] = sum;
    }
    __syncthreads();
    for (int i = tid; i < 1024; i += 256)
      idn[g * 1024 + i] = 1.f / (rsum[i >> 5] * rsum[i & 31]);
  }
}

// ---------------------------------------------------------------------------
// qkv implicit GEMM (unchanged). grid = 256, XCD-swizzled.
// ---------------------------------------------------------------------------
__global__ __launch_bounds__(512, 1) void qkv_gemm_kernel(
    const u16* __restrict__ wA, const u16* __restrict__ xT,
    const u16* __restrict__ zpage, const float* __restrict__ idn,
    u16* __restrict__ qt, u16* __restrict__ ktp, u16* __restrict__ vt) {
  const int tid = threadIdx.x;
  const int lane = tid & 63;
  const int wv = tid >> 6;
  const int wm = wv >> 2, wn = wv & 3;
  const int h = lane >> 4, l15 = lane & 15;
  const int wgid = ((int)blockIdx.x & 7) * 32 + ((int)blockIdx.x >> 3);
  const int bm = wgid & 7;
  const int bn = wgid >> 3;
  const int m0 = bm * 192;

  __shared__ __align__(16) u16 smem[57344];

  const int arow = tid >> 3;
  const int aslot = (tid & 7) ^ (arow & 7);
  const u16* gA0 = wA + (size_t)(m0 + arow) * KK + aslot * 8;
  const int bslot8 = ((tid & 3) ^ (((tid >> 2) & 3) ^ ((tid >> 4) & 3))) * 8;
  const int pimgBase = ((bn & 3) << 8) + (tid >> 2);
  const u16* xTb = xT + (size_t)(bn >> 2) * (1024 * 256);

  auto mkSrc = [&](int tap, int pass) -> const u16* {
    const int dyq = (tap * 11) >> 5;
    const int ddx = tap - 3 * dyq - 1;
    const int ddy = dyq - 1;
    const int pimg = pimgBase + pass * 128;
    const int sx = (pimg & 31) + ddx;
    const int sy = (pimg >> 5) + ddy;
    if (((unsigned)sx < 32u) && ((unsigned)sy < 32u))
      return xTb + (size_t)(pimg + ddx + ddy * 32) * 256 + bslot8;
    return zpage;
  };
  const u16* srcB0 = mkSrc(0, 0);
  const u16* srcB1 = mkSrc(0, 1);
  int koff = 0;

  const int aX = l15 & 7;
  const int bX = (l15 & 3) ^ ((l15 >> 2) & 3);
  const u16* aBase = smem + (wm * 96 + l15) * 64;
  const u16* bBase = smem + 12288 + (wn * 64 + l15) * 32;
  const int slA0 = (h ^ aX) * 8;
  const int slA1 = ((4 + h) ^ aX) * 8;
  const int slB = (h ^ bX) * 8;

  f32x4 acc[6][4];
#pragma unroll
  for (int i = 0; i < 6; ++i)
#pragma unroll
    for (int j = 0; j < 4; ++j) acc[i][j] = (f32x4){0.f, 0.f, 0.f, 0.f};

  auto STAGE_A = [&](int pass, int dbuf, int kti) {
    gl16(gA0 + (size_t)pass * 64 * KK + kti * 64,
         smem + dbuf + pass * 4096 + tid * 8);
  };
  auto STAGE_B = [&](int kap, int pass, int dbuf) {
    gl16((pass ? srcB1 : srcB0) + koff + kap * 32,
         smem + dbuf + 12288 + kap * 8192 + pass * 4096 + tid * 8);
  };

  STAGE_A(0, 0, 0); STAGE_A(1, 0, 0); STAGE_A(2, 0, 0);
  STAGE_B(0, 0, 0); STAGE_B(0, 1, 0);
  STAGE_B(1, 0, 0); STAGE_B(1, 1, 0);
  asm volatile("s_waitcnt vmcnt(2)" ::: "memory");
  barrier_raw();

  bf16x8 af[3], bf[4];
#pragma unroll 1
  for (int kt = 0; kt < 36; ++kt) {
    const int buf = (kt & 1) * 28672;
    const int nbuf = 28672 - buf;
    const bool more = (kt < 35);

    if (more && (kt & 3) == 3) {
      const int ntap = (kt + 1) >> 2;
      srcB0 = mkSrc(ntap, 0);
      srcB1 = mkSrc(ntap, 1);
    }
    koff = ((kt + 1) & 3) << 6;

    // ---- P1 ----
#pragma unroll
    for (int ni = 0; ni < 4; ++ni) bf[ni] = ld8(bBase + buf + ni * 512 + slB);
#pragma unroll
    for (int q = 0; q < 3; ++q) af[q] = ld8(aBase + buf + q * 1024 + slA0);
    if (more) { STAGE_A(0, nbuf, kt + 1); STAGE_A(1, nbuf, kt + 1); }
    barrier_raw();
    __builtin_amdgcn_s_setprio(1);
#pragma unroll
    for (int q = 0; q < 3; ++q)
#pragma unroll
      for (int ni = 0; ni < 4; ++ni)
        acc[q][ni] = __builtin_amdgcn_mfma_f32_16x16x32_bf16(af[q], bf[ni], acc[q][ni], 0, 0, 0);
    __builtin_amdgcn_s_setprio(0);

    // ---- P2 ----
#pragma unroll
    for (int q = 0; q < 3; ++q) af[q] = ld8(aBase + buf + (3 + q) * 1024 + slA0);
    if (more) {
      STAGE_A(2, nbuf, kt + 1); STAGE_B(0, 0, nbuf);
      asm volatile("s_waitcnt vmcnt(4)" ::: "memory");
    } else {
      asm volatile("s_waitcnt vmcnt(0)" ::: "memory");
    }
    barrier_raw();
    __builtin_amdgcn_s_setprio(1);
#pragma unroll
    for (int q = 0; q < 3; ++q)
#pragma unroll
      for (int ni = 0; ni < 4; ++ni)
        acc[3 + q][ni] = __builtin_amdgcn_mfma_f32_16x16x32_bf16(af[q], bf[ni], acc[3 + q][ni], 0, 0, 0);
    __builtin_amdgcn_s_setprio(0);

    // ---- P3 ----
#pragma unroll
    for (int ni = 0; ni < 4; ++ni) bf[ni] = ld8(bBase + buf + 8192 + ni * 512 + slB);
#pragma unroll
    for (int q = 0; q < 3; ++q) af[q] = ld8(aBase + buf + q * 1024 + slA1);
    if (more) { STAGE_B(0, 1, nbuf); STAGE_B(1, 0, nbuf); }
    barrier_raw();
    __builtin_amdgcn_s_setprio(1);
#pragma unroll
    for (int q = 0; q < 3; ++q)
#pragma unroll
      for (int ni = 0; ni < 4; ++ni)
        acc[q][ni] = __builtin_amdgcn_mfma_f32_16x16x32_bf16(af[q], bf[ni], acc[q][ni], 0, 0, 0);
    __builtin_amdgcn_s_setprio(0);

    // ---- P4 ----
#pragma unroll
    for (int q = 0; q < 3; ++q) af[q] = ld8(aBase + buf + (3 + q) * 1024 + slA1);
    if (more) {
      STAGE_B(1, 1, nbuf);
      asm volatile("s_waitcnt vmcnt(2)" ::: "memory");
    }
    barrier_raw();
    __builtin_amdgcn_s_setprio(1);
#pragma unroll
    for (int q = 0; q < 3; ++q)
#pragma unroll
      for (int ni = 0; ni < 4; ++ni)
        acc[3 + q][ni] = __builtin_amdgcn_mfma_f32_16x16x32_bf16(af[q], bf[ni], acc[3 + q][ni], 0, 0, 0);
    __builtin_amdgcn_s_setprio(0);
  }

  const int b = bn >> 2;
  const int nimgBase = (bn & 3) * 256 + wn * 64;
  float ssF[4], ssH[4];
#pragma unroll
  for (int ni = 0; ni < 4; ++ni) {
    float sF = 0.f, sH = 0.f;
#pragma unroll
    for (int m4 = 0; m4 < 6; ++m4) {
      float s = 0.f;
#pragma unroll
      for (int r = 0; r < 4; ++r) s += acc[m4][ni][r] * acc[m4][ni][r];
      const bool isFull = (wm == 0) ? (m4 < 4) : (m4 >= 2);
      if (isFull) sF += s; else sH += s;
    }
    sF += __shfl_xor(sF, 16, 64); sF += __shfl_xor(sF, 32, 64);
    sH += __shfl_xor(sH, 16, 64); sH += __shfl_xor(sH, 32, 64);
    ssF[ni] = sF; ssH[ni] = sH;
  }
  float* xch = (float*)smem;
  if (h == 0) {
#pragma unroll
    for (int ni = 0; ni < 4; ++ni)
      xch[((wm * 4 + wn) * 4 + ni) * 16 + l15] = ssH[ni];
  }
  __syncthreads();
#pragma unroll
  for (int ni = 0; ni < 4; ++ni)
    ssH[ni] += xch[(((1 - wm) * 4 + wn) * 4 + ni) * 16 + l15];

  const int headF = (wm == 0) ? 3 * bm : 3 * bm + 2;
  const int headH = 3 * bm + 1;
  const int secF = headF >> 3, gF = headF & 7;
  const int secH = headH >> 3, gH = headH & 7;
  float rsF[4], rsH[4];
#pragma unroll
  for (int ni = 0; ni < 4; ++ni) {
    const int nimg = nimgBase + ni * 16 + l15;
    float rf = rsqrtf(ssF[ni] + SMOOTH);
    if (secF == 0) rf *= idn[gF * 1024 + nimg];
    rsF[ni] = rf;
    float rh = rsqrtf(ssH[ni] + SMOOTH);
    if (secH == 0) rh *= idn[gH * 1024 + nimg];
    rsH[ni] = rh;
  }
#pragma unroll
  for (int m4 = 0; m4 < 6; ++m4) {
    const bool isFull = (wm == 0) ? (m4 < 4) : (m4 >= 2);
    const int head = isFull ? headF : headH;
    const int sec = head >> 3, g = head & 7;
    const int d0 = isFull ? ((wm == 0) ? m4 * 16 : (m4 - 2) * 16)
                          : ((wm == 0) ? (m4 - 4) * 16 : 32 + m4 * 16);
    const size_t bg = (size_t)b * G + g;
    if (sec < 2) {
      u16* basep = (sec ? ktp : qt) + bg * 65536;
#pragma unroll
      for (int ni = 0; ni < 4; ++ni) {
        const float rs = isFull ? rsF[ni] : rsH[ni];
        const int nimg = nimgBase + ni * 16 + l15;
        us4 v;
        v[0] = f2bf(acc[m4][ni][0] * rs);
        v[1] = f2bf(acc[m4][ni][1] * rs);
        v[2] = f2bf(acc[m4][ni][2] * rs);
        v[3] = f2bf(acc[m4][ni][3] * rs);
        *reinterpret_cast<us4*>(basep + (size_t)nimg * 64 + d0 + 4 * h) = v;
      }
    } else {
      u16* basep = vt + bg * 65536;
#pragma unroll
      for (int ni = 0; ni < 4; ++ni) {
        const int nimg = nimgBase + ni * 16 + l15;
#pragma unroll
        for (int r = 0; r < 4; ++r)
          basep[(size_t)(d0 + 4 * h + r) * 1024 + nimg] = f2bf(acc[m4][ni][r]);
      }
    }
  }
}

// ---------------------------------------------------------------------------
// MFMA attention (R14 known-good): QBLK=128, sQ LDS-staged, Q fragments
// hoisted after sync, K/V double-buffered, one __syncthreads per m-tile.
// LDS 64KB -> 2 blocks/CU. grid = 512, XCD-swizzled by head g.
// ---------------------------------------------------------------------------
__global__ __launch_bounds__(256, 2) void attn_mfma_kernel(
    const u16* __restrict__ qt, const u16* __restrict__ ktp,
    const u16* __restrict__ vt, const float* __restrict__ etab,
    u16* __restrict__ aout) {
  const int tid = threadIdx.x;
  const int lane = tid & 63;
  const int wv = tid >> 6;
  const int h = lane >> 4;
  const int l15 = lane & 15;
  const int wgid = (blockIdx.x & 7) * 64 + (blockIdx.x >> 3);
  const int g = wgid >> 6;
  const int b = (wgid >> 3) & 7;
  const int nb = wgid & 7;

  __shared__ __align__(16) u16 smem[32768];  // 64 KB
  __shared__ float etabL[64];
  u16* sQ = smem;
  u16* sP = smem + 24576 + wv * 2048;

  const size_t bg = (size_t)b * G + g;
  const u16* qg = qt + bg * 65536;
  const u16* kg = ktp + bg * 65536;
  const u16* vg = vt + bg * 65536;

  if (tid < 64) etabL[tid] = etab[g * 64 + tid];

  const int srow = tid >> 3;
  const int scol = ((tid & 7) ^ (srow & 7)) * 8;

#pragma unroll
  for (int pass = 0; pass < 4; ++pass)
    gl16(qg + (size_t)(nb * 128 + pass * 32 + srow) * 64 + scol,
         sQ + pass * 2048 + tid * 8);
#pragma unroll
  for (int pass = 0; pass < 2; ++pass) {
    gl16(kg + (size_t)(pass * 32 + srow) * 64 + scol,
         smem + 8192 + pass * 2048 + tid * 8);
    gl16(vg + (size_t)(pass * 32 + srow) * 1024 + scol,
         smem + 16384 + pass * 2048 + tid * 8);
  }
  __syncthreads();

  const int col8 = h * 8;

  // hoist Q fragments (loop-invariant across all 16 m-tiles)
  bf16x8 aq[2][2];
#pragma unroll
  for (int kk = 0; kk < 2; ++kk) {
    aq[kk][0] = ldfrag(sQ, wv * 32 + l15, kk * 32 + col8);
    aq[kk][1] = ldfrag(sQ, wv * 32 + 16 + l15, kk * 32 + col8);
  }

  float exv[2][4][2];
  int ynr[2][4];
#pragma unroll
  for (int ti = 0; ti < 2; ++ti)
#pragma unroll
    for (int r = 0; r < 4; ++r) {
      int n = nb * 128 + wv * 32 + ti * 16 + 4 * h + r;
      int xn = n & 31;
      ynr[ti][r] = n >> 5;
      exv[ti][r][0] = etabL[xn - l15 + 31];
      exv[ti][r][1] = etabL[xn - l15 + 15];
    }

  f32x4 oacc[2][4];
#pragma unroll
  for (int ti = 0; ti < 2; ++ti)
#pragma unroll
    for (int dj = 0; dj < 4; ++dj) oacc[ti][dj] = (f32x4){0.f, 0.f, 0.f, 0.f};

  for (int mt = 0; mt < 16; ++mt) {
    const u16* sKb = smem + 8192 + (mt & 1) * 4096;
    const u16* sVb = smem + 16384 + (mt & 1) * 4096;
    if (mt < 15) {
      const int nt2 = mt + 1;
      const int d = nt2 & 1;
#pragma unroll
      for (int pass = 0; pass < 2; ++pass) {
        gl16(kg + (size_t)(nt2 * 64 + pass * 32 + srow) * 64 + scol,
             smem + 8192 + d * 4096 + pass * 2048 + tid * 8);
        gl16(vg + (size_t)(pass * 32 + srow) * 1024 + nt2 * 64 + scol,
             smem + 16384 + d * 4096 + pass * 2048 + tid * 8);
      }
    }

    float eyv[2][4][2];
#pragma unroll
    for (int ti = 0; ti < 2; ++ti)
#pragma unroll
      for (int r = 0; r < 4; ++r) {
        eyv[ti][r][0] = etabL[ynr[ti][r] - 2 * mt + 31];
        eyv[ti][r][1] = etabL[ynr[ti][r] - 2 * mt + 30];
      }

    f32x4 sacc[2][4];
#pragma unroll
    for (int ti = 0; ti < 2; ++ti)
#pragma unroll
      for (int tj = 0; tj < 4; ++tj) sacc[ti][tj] = (f32x4){0.f, 0.f, 0.f, 0.f};
#pragma unroll
    for (int kk = 0; kk < 2; ++kk) {
#pragma unroll
      for (int tj = 0; tj < 4; ++tj) {
        bf16x8 bk = ldfrag(sKb, tj * 16 + l15, kk * 32 + col8);
        sacc[0][tj] = __builtin_amdgcn_mfma_f32_16x16x32_bf16(aq[kk][0], bk, sacc[0][tj], 0, 0, 0);
        sacc[1][tj] = __builtin_amdgcn_mfma_f32_16x16x32_bf16(aq[kk][1], bk, sacc[1][tj], 0, 0, 0);
      }
    }

#pragma unroll
    for (int tj = 0; tj < 4; ++tj) {
#pragma unroll
      for (int ti = 0; ti < 2; ++ti) {
#pragma unroll
        for (int r = 0; r < 4; ++r) {
          float wgt = sacc[ti][tj][r] * (eyv[ti][r][tj >> 1] * exv[ti][r][tj & 1]);
          int nl = ti * 16 + 4 * h + r;
          int pidx = (nl * 64 + tj * 16 + l15) ^ ((nl & 7) << 3);
          sP[pidx] = f2bf(wgt);
        }
      }
    }

#pragma unroll
    for (int km = 0; km < 2; ++km) {
      bf16x8 ap0 = ldfrag(sP, l15, km * 32 + col8);
      bf16x8 ap1 = ldfrag(sP, 16 + l15, km * 32 + col8);
#pragma unroll
      for (int dj = 0; dj < 4; ++dj) {
        bf16x8 bvv = ldfrag(sVb, dj * 16 + l15, km * 32 + col8);
        oacc[0][dj] = __builtin_amdgcn_mfma_f32_16x16x32_bf16(ap0, bvv, oacc[0][dj], 0, 0, 0);
        oacc[1][dj] = __builtin_amdgcn_mfma_f32_16x16x32_bf16(ap1, bvv, oacc[1][dj], 0, 0, 0);
      }
    }
    __syncthreads();
  }

  u16* sO = smem + 8192;
#pragma unroll
  for (int ti = 0; ti < 2; ++ti)
#pragma unroll
    for (int dj = 0; dj < 4; ++dj)
#pragma unroll
      for (int r = 0; r < 4; ++r) {
        int nl = wv * 32 + ti * 16 + 4 * h + r;
        int idx = (nl * 64 + dj * 16 + l15) ^ ((nl & 7) << 3);
        sO[idx] = f2bf(oacc[ti][dj][r]);
      }
  __syncthreads();
  {
    const int row = tid >> 1, c = (tid & 1) * 4;
    us8* dst = reinterpret_cast<us8*>(aout + (bg * 1024 + (size_t)nb * 128 + row) * 64);
#pragma unroll
    for (int k = 0; k < 4; ++k) {
      int idx = (row * 64 + (c + k) * 8) ^ ((row & 7) << 3);
      dst[c + k] = *reinterpret_cast<const us8*>(sO + idx);
    }
  }
}

// ---------------------------------------------------------------------------
// 1x1 conv as MFMA GEMM + fused deterministic BN partial stats. grid = 512.
// ---------------------------------------------------------------------------
__global__ __launch_bounds__(256, 4) void conv1x1_mfma_kernel(
    const u16* __restrict__ aout, const u16* __restrict__ wB,
    u16* __restrict__ proj, float* __restrict__ partials) {
  const int tid = threadIdx.x;
  const int lane = tid & 63;
  const int wv = tid >> 6;
  const int wr = wv >> 1, wc = wv & 1;
  const int h = lane >> 4, l15 = lane & 15;
  const int bm = blockIdx.x & 3;
  const int ntile = blockIdx.x >> 2;
  const int b = ntile >> 4;
  const int n0 = (ntile & 15) * 64;
  const int c0 = bm * 64;

  __shared__ __align__(16) u16 smem[16384];

  f32x4 acc[2][2];
#pragma unroll
  for (int i = 0; i < 2; ++i)
#pragma unroll
    for (int j = 0; j < 2; ++j) acc[i][j] = (f32x4){0.f, 0.f, 0.f, 0.f};

  const int srow = tid >> 3;
  const int scol = (tid & 7) * 8;

  auto STG = [&](int ks) {
    const int d = ks & 1;
#pragma unroll
    for (int pass = 0; pass < 2; ++pass) {
      gl16(wB + (size_t)(c0 + pass * 32 + srow) * 512 + ks * 64 + scol,
           smem + d * 4096 + pass * 2048 + tid * 8);
      gl16(aout + ((size_t)(b * G + ks) * 1024 + n0 + pass * 32 + srow) * 64 + scol,
           smem + 8192 + d * 4096 + pass * 2048 + tid * 8);
    }
  };

  STG(0);
  __syncthreads();
  for (int ks = 0; ks < 8; ++ks) {
    if (ks < 7) STG(ks + 1);
    const u16* sA = smem + (ks & 1) * 4096;
    const u16* sB = smem + 8192 + (ks & 1) * 4096;
#pragma unroll
    for (int kk = 0; kk < 2; ++kk) {
      bf16x8 af[2], bv[2];
#pragma unroll
      for (int mt = 0; mt < 2; ++mt)
        af[mt] = ld8(sA + (wr * 32 + mt * 16 + l15) * 64 + kk * 32 + h * 8);
#pragma unroll
      for (int nt = 0; nt < 2; ++nt)
        bv[nt] = ld8(sB + (wc * 32 + nt * 16 + l15) * 64 + kk * 32 + h * 8);
#pragma unroll
      for (int mt = 0; mt < 2; ++mt)
#pragma unroll
        for (int nt = 0; nt < 2; ++nt)
          acc[mt][nt] = __builtin_amdgcn_mfma_f32_16x16x32_bf16(af[mt], bv[nt], acc[mt][nt], 0, 0, 0);
    }
    __syncthreads();
  }

#pragma unroll
  for (int mt = 0; mt < 2; ++mt)
#pragma unroll
    for (int nt = 0; nt < 2; ++nt)
#pragma unroll
      for (int r = 0; r < 4; ++r) {
        const int c = c0 + wr * 32 + mt * 16 + 4 * h + r;
        const int n = n0 + wc * 32 + nt * 16 + l15;
        proj[((size_t)b * Cc + c) * Nn + n] = f2bf(acc[mt][nt][r]);
      }

  const int slab = ((b * 16 + (ntile & 15)) << 1) + wc;
#pragma unroll
  for (int mt = 0; mt < 2; ++mt)
#pragma unroll
    for (int r = 0; r < 4; ++r) {
      float s1 = acc[mt][0][r] + acc[mt][1][r];
      float s2 = acc[mt][0][r] * acc[mt][0][r] + acc[mt][1][r] * acc[mt][1][r];
#pragma unroll
      for (int o = 8; o >= 1; o >>= 1) {
        s1 += __shfl_xor(s1, o, 64);
        s2 += __shfl_xor(s2, o, 64);
      }
      if (l15 == 0) {
        const int c = c0 + wr * 32 + mt * 16 + 4 * h + r;
        partials[(size_t)c * 256 + slab] = s1;
        partials[65536 + (size_t)c * 256 + slab] = s2;
      }
    }
}

// ---------------------------------------------------------------------------
// BN apply with FUSED in-block stats (replaces bn_reduce + bn_apply):
// each block covers one (b,c) row; c = blockIdx.x & 255 is block-uniform, so
// the block redundantly reduces that channel's 256 partials with the exact
// same reduction sequence the old bn_reduce used (bit-identical stats).
// grid = 8192 blocks of 256.
// ---------------------------------------------------------------------------
__global__ __launch_bounds__(256) void bn_apply_kernel(
    const u16* __restrict__ proj, const float* __restrict__ partials,
    const float* __restrict__ gamma, const float* __restrict__ beta,
    float* __restrict__ out) {
  const int tid = threadIdx.x;
  const int c = blockIdx.x & (Cc - 1);  // block-uniform channel

  // in-block stats (identical sequence to the old bn_reduce)
  float s1 = partials[(size_t)c * 256 + tid];
  float s2 = partials[65536 + (size_t)c * 256 + tid];
  s1 = waveSum(s1);
  s2 = waveSum(s2);
  __shared__ float r1[4], r2[4];
  if ((tid & 63) == 0) { r1[tid >> 6] = s1; r2[tid >> 6] = s2; }
  __syncthreads();
  const float S = r1[0] + r1[1] + r1[2] + r1[3];
  const float S2 = r2[0] + r2[1] + r2[2] + r2[3];
  const float invM = 1.f / (float)(Bn * Nn);
  const float mean = S * invM;
  const float var = S2 * invM - mean * mean;
  const float rstd = rsqrtf(var + BN_EPS);

  const int idx = blockIdx.x * 256 + tid;  // us4 chunk
  us4 v = reinterpret_cast<const us4*>(proj)[idx];
  const float sc = rstd * gamma[c];
  const float sh = beta[c];
  float4 o;
  o.x = fmaxf((bf2f(v[0]) - mean) * sc + sh, 0.f);
  o.y = fmaxf((bf2f(v[1]) - mean) * sc + sh, 0.f);
  o.z = fmaxf((bf2f(v[2]) - mean) * sc + sh, 0.f);
  o.w = fmaxf((bf2f(v[3]) - mean) * sc + sh, 0.f);
  reinterpret_cast<float4*>(out)[idx] = o;
}

// ---------------------------------------------------------------------------
extern "C" void kernel_launch(void* const* d_in, const int* in_sizes, int n_in,
                              void* d_out, int out_size, void* d_ws, size_t ws_size,
                              hipStream_t stream) {
  const float* x = (const float*)d_in[0];
  const float* w_qkv = (const float*)d_in[1];
  const float* head_scale = (const float*)d_in[2];
  const float* w_out = (const float*)d_in[3];
  const float* gamma = (const float*)d_in[4];
  const float* beta = (const float*)d_in[5];
  float* out = (float*)d_out;

  char* w = (char*)d_ws;
  u16* qt = (u16*)(w + 0);                 // 8 MB
  u16* kt = (u16*)(w + 8388608);           // 8 MB
  u16* vt = (u16*)(w + 16777216);          // 8 MB
  u16* wA = (u16*)(w + 25165824);          // 7 MB (dead after qkv GEMM)
  u16* aout = (u16*)(w + 25165824);        // 8 MB (written post-GEMM, by attn)
  u16* xT = (u16*)(w + 33554432);          // 4.2 MB (dead after qkv GEMM)
  float* partials = (float*)(w + 33554432); // 512 KB, overlays dead xT
  u16* proj = (u16*)(w + 37748736);        // 4 MB bf16
  float* etab = (float*)(w + 71303168);    // 2 KB
  float* idn = (float*)(w + 71305216);     // 32 KB
  u16* zpage = (u16*)(w + 71337984);       // 512 B (zeroed by prep)
  u16* wB = (u16*)(w + 71862272);          // 256 KB

  prep_kernel<<<dim3(2120), dim3(256), 0, stream>>>(
      w_qkv, w_out, x, head_scale, wA, wB, xT, zpage, etab, idn);
  qkv_gemm_kernel<<<dim3(256), dim3(512), 0, stream>>>(wA, xT, zpage, idn, qt, kt, vt);
  attn_mfma_kernel<<<dim3(512), dim3(256), 0, stream>>>(qt, kt, vt, etab, aout);
  conv1x1_mfma_kernel<<<dim3(512), dim3(256), 0, stream>>>(aout, wB, proj, partials);
  bn_apply_kernel<<<dim3(Bn * Cc), dim3(256), 0, stream>>>(proj, partials, gamma, beta, out);
}